// Round 6
// baseline (11035.954 us; speedup 1.0000x reference)
//
#include <hip/hip_runtime.h>
#include <math.h>

// ---------------- problem constants ----------------
constexpr int TT = 256, BB = 16, DD = 512;
constexpr int NTOK = 4096;                 // T*B
constexpr int RTOT = 3456;                 // 768 + 384 + 768 + 1536
constexpr int E1OFF = 768, E2OFF = 1152, E3OFF = 1920;

// ---------------- workspace layout (bytes) ----------------
constexpr size_t OFF_TSUM = 0;                                   // 4 f
constexpr size_t OFF_TCNT = 16;                                  // 4 f
constexpr size_t OFF_CNT  = 32;                                  // 8 ints (XCD claim counters)
constexpr size_t ZBYTES   = 64;
constexpr size_t OFF_GI   = 4096;
constexpr size_t OFF_HS   = OFF_GI  + (size_t)NTOK*RTOT*4;       // router h history (poll target)
constexpr size_t OFF_HA3  = OFF_HS  + (size_t)NTOK*256*4;
constexpr size_t OFF_HA2  = OFF_HA3 + (size_t)NTOK*512*4;
constexpr size_t OFF_HA1  = OFF_HA2 + (size_t)NTOK*256*4;
constexpr size_t OFF_AP   = OFF_HA1 + (size_t)NTOK*128*4;
constexpr size_t OFF_MU   = OFF_AP  + (size_t)NTOK*896*4;
constexpr size_t OFF_RSTD = OFF_MU  + 896*4;
constexpr size_t POISON_BYTES = (size_t)NTOK*(256+512+256+128)*4;  // HS..HA1 contiguous

__device__ __forceinline__ bool is_poison(float v) {
  return __float_as_uint(v) == 0xAAAAAAAAu;
}

// fast, clamped activations (~2ulp; validated in R5: absmax unchanged)
__device__ __forceinline__ float fast_sigmoid(float x) {
  const float xc = fminf(fmaxf(x, -30.f), 30.f);
  return __fdividef(1.f, 1.f + __expf(-xc));
}
__device__ __forceinline__ float fast_tanh(float x) {
  const float xc = fminf(fmaxf(x, -15.f), 15.f);
  const float e = __expf(-2.f * xc);
  return (1.f - e) * __fdividef(1.f, 1.f + e);
}

// ================= phase 1: gi = x @ Wih^T + b_ih (all 3456 rows) =================
__global__ __launch_bounds__(256) void gemm1_kernel(
    const float* __restrict__ X,
    const float* __restrict__ wR, const float* __restrict__ w1,
    const float* __restrict__ w2, const float* __restrict__ w3,
    const float* __restrict__ bR, const float* __restrict__ b1,
    const float* __restrict__ b2, const float* __restrict__ b3,
    float* __restrict__ GI)
{
  __shared__ float At[32*64];
  __shared__ float Bt[32*64];
  const int n0 = blockIdx.x * 64;
  const int r0 = blockIdx.y * 64;
  const float* W; const float* bias; int rs;
  if (r0 < 768)       { W = wR; bias = bR; rs = 0; }
  else if (r0 < 1152) { W = w1; bias = b1; rs = 768; }
  else if (r0 < 1920) { W = w2; bias = b2; rs = 1152; }
  else                { W = w3; bias = b3; rs = 1920; }
  const int lr0 = r0 - rs;
  const int tid = threadIdx.x;
  const int lm = tid & 63, lk4 = tid >> 6;
  const int tx = tid & 15, ty = tid >> 4;
  float acc[4][4];
#pragma unroll
  for (int i = 0; i < 4; ++i)
#pragma unroll
    for (int q = 0; q < 4; ++q) acc[i][q] = 0.f;

  for (int kb = 0; kb < 512; kb += 32) {
    const float4 a0 = *(const float4*)(X + (size_t)(n0+lm)*512 + kb + lk4*8);
    const float4 a1 = *(const float4*)(X + (size_t)(n0+lm)*512 + kb + lk4*8 + 4);
    const float4 c0 = *(const float4*)(W + (size_t)(lr0+lm)*512 + kb + lk4*8);
    const float4 c1 = *(const float4*)(W + (size_t)(lr0+lm)*512 + kb + lk4*8 + 4);
    __syncthreads();
    At[(lk4*8+0)*64+lm]=a0.x; At[(lk4*8+1)*64+lm]=a0.y; At[(lk4*8+2)*64+lm]=a0.z; At[(lk4*8+3)*64+lm]=a0.w;
    At[(lk4*8+4)*64+lm]=a1.x; At[(lk4*8+5)*64+lm]=a1.y; At[(lk4*8+6)*64+lm]=a1.z; At[(lk4*8+7)*64+lm]=a1.w;
    Bt[(lk4*8+0)*64+lm]=c0.x; Bt[(lk4*8+1)*64+lm]=c0.y; Bt[(lk4*8+2)*64+lm]=c0.z; Bt[(lk4*8+3)*64+lm]=c0.w;
    Bt[(lk4*8+4)*64+lm]=c1.x; Bt[(lk4*8+5)*64+lm]=c1.y; Bt[(lk4*8+6)*64+lm]=c1.z; Bt[(lk4*8+7)*64+lm]=c1.w;
    __syncthreads();
#pragma unroll
    for (int k = 0; k < 32; ++k) {
      const float4 av = *(const float4*)&At[k*64 + ty*4];
      const float4 bv = *(const float4*)&Bt[k*64 + tx*4];
      acc[0][0]=fmaf(av.x,bv.x,acc[0][0]); acc[0][1]=fmaf(av.x,bv.y,acc[0][1]); acc[0][2]=fmaf(av.x,bv.z,acc[0][2]); acc[0][3]=fmaf(av.x,bv.w,acc[0][3]);
      acc[1][0]=fmaf(av.y,bv.x,acc[1][0]); acc[1][1]=fmaf(av.y,bv.y,acc[1][1]); acc[1][2]=fmaf(av.y,bv.z,acc[1][2]); acc[1][3]=fmaf(av.y,bv.w,acc[1][3]);
      acc[2][0]=fmaf(av.z,bv.x,acc[2][0]); acc[2][1]=fmaf(av.z,bv.y,acc[2][1]); acc[2][2]=fmaf(av.z,bv.z,acc[2][2]); acc[2][3]=fmaf(av.z,bv.w,acc[2][3]);
      acc[3][0]=fmaf(av.w,bv.x,acc[3][0]); acc[3][1]=fmaf(av.w,bv.y,acc[3][1]); acc[3][2]=fmaf(av.w,bv.z,acc[3][2]); acc[3][3]=fmaf(av.w,bv.w,acc[3][3]);
    }
  }
  const float4 bb = *(const float4*)(bias + lr0 + tx*4);
#pragma unroll
  for (int i = 0; i < 4; ++i) {
    float4 o;
    o.x = acc[i][0] + bb.x; o.y = acc[i][1] + bb.y; o.z = acc[i][2] + bb.z; o.w = acc[i][3] + bb.w;
    *(float4*)(GI + (size_t)(n0+ty*4+i)*RTOT + r0 + tx*4) = o;
  }
}

// ================= phase 2a: e1 single-WG scan (LDS-only exchange, DIAGNOSTIC) =====
// One 1024-thread WG. 128 outputs x 8 lanes (KCN=8). No global polling, no
// cross-WG hop: per-step chain = LDS read + 48 FMA + 3 shfl + gates + barrier.
// Its rocprof duration is a clean measurement of the pure LDS-chain floor.
__global__ __launch_bounds__(1024, 1) void e1_scan_kernel(
    const float* __restrict__ GIe, const float* __restrict__ whh,
    const float* __restrict__ bhh, float* __restrict__ hall)
{
  constexpr int H = 128, CHUNK = 16, NF4 = 4;
  __shared__ __attribute__((aligned(16))) float sm[2 * H];
  const int tid = threadIdx.x;
  const int lane = tid & 63;
  const int j = tid >> 3;          // [0,128)
  const int kc = tid & 7;

  float4 wr[NF4], wz[NF4], wn[NF4];   // 12 float4 = 48 VGPR, resident
#pragma unroll
  for (int i4 = 0; i4 < NF4; ++i4) {
    const int kk = kc * CHUNK + ((i4 + kc) & (NF4 - 1)) * 4;
    wr[i4] = *(const float4*)(whh + (size_t)j * H + kk);
    wz[i4] = *(const float4*)(whh + (size_t)(H + j) * H + kk);
    wn[i4] = *(const float4*)(whh + (size_t)(2*H + j) * H + kk);
  }
  float gbr = 0.f, gbz = 0.f, gbn = 0.f, hprev = 0.f;
  if (kc == 0) { gbr = bhh[j]; gbz = bhh[H + j]; gbn = bhh[2*H + j]; }

  // gi: 16-token superblock, 2 tokens/lane (kc and kc+8); reload every 16 steps
  float gA0r, gA0z, gA0n, gA1r, gA1z, gA1n;
  float gB0r, gB0z, gB0n, gB1r, gB1z, gB1n;
  { const float* g = GIe + (size_t)kc * RTOT;       gA0r=g[j]; gA0z=g[H+j]; gA0n=g[2*H+j]; }
  { const float* g = GIe + (size_t)(8+kc) * RTOT;   gA1r=g[j]; gA1z=g[H+j]; gA1n=g[2*H+j]; }
  { const float* g = GIe + (size_t)(16+kc) * RTOT;  gB0r=g[j]; gB0z=g[H+j]; gB0n=g[2*H+j]; }
  { const float* g = GIe + (size_t)(24+kc) * RTOT;  gB1r=g[j]; gB1z=g[H+j]; gB1n=g[2*H+j]; }

  if (tid < H) sm[tid] = 0.f;    // parity-0 buffer = h_{-1}
  __syncthreads();

  for (int t = 0; t < NTOK; ++t) {
    if ((t & 15) == 0 && t > 0) {          // rotate superblock, prefetch next 16
      gA0r=gB0r; gA0z=gB0z; gA0n=gB0n; gA1r=gB1r; gA1z=gB1z; gA1n=gB1n;
      const int nb = t + 16;
      if (nb + kc < NTOK) {
        const float* g0 = GIe + (size_t)(nb + kc) * RTOT;
        gB0r=g0[j]; gB0z=g0[H+j]; gB0n=g0[2*H+j];
      }
      if (nb + 8 + kc < NTOK) {
        const float* g1 = GIe + (size_t)(nb + 8 + kc) * RTOT;
        gB1r=g1[j]; gB1z=g1[H+j]; gB1n=g1[2*H+j];
      }
    }
    const int hi = (t >> 3) & 1;           // wave-uniform select (no dyn index)
    const float sr = hi ? gA1r : gA0r;
    const float sz = hi ? gA1z : gA0z;
    const float sn = hi ? gA1n : gA0n;
    const int src = (lane & ~7) | (t & 7);
    const float gr0 = __shfl(sr, src);
    const float gz0 = __shfl(sz, src);
    const float gn0 = __shfl(sn, src);

    const float* hbuf = sm + (size_t)(t & 1) * H;
    float pr = 0.f, pz = 0.f, pn = 0.f;
#pragma unroll
    for (int i4 = 0; i4 < NF4; ++i4) {
      const float4 h4 = *(const float4*)(hbuf + kc * CHUNK + ((i4 + kc) & (NF4 - 1)) * 4);
      pr = fmaf(wr[i4].x, h4.x, pr); pr = fmaf(wr[i4].y, h4.y, pr);
      pr = fmaf(wr[i4].z, h4.z, pr); pr = fmaf(wr[i4].w, h4.w, pr);
      pz = fmaf(wz[i4].x, h4.x, pz); pz = fmaf(wz[i4].y, h4.y, pz);
      pz = fmaf(wz[i4].z, h4.z, pz); pz = fmaf(wz[i4].w, h4.w, pz);
      pn = fmaf(wn[i4].x, h4.x, pn); pn = fmaf(wn[i4].y, h4.y, pn);
      pn = fmaf(wn[i4].z, h4.z, pn); pn = fmaf(wn[i4].w, h4.w, pn);
    }
    pr += __shfl_down(pr, 4); pz += __shfl_down(pz, 4); pn += __shfl_down(pn, 4);
    pr += __shfl_down(pr, 2); pz += __shfl_down(pz, 2); pn += __shfl_down(pn, 2);
    pr += __shfl_down(pr, 1); pz += __shfl_down(pz, 1); pn += __shfl_down(pn, 1);
    if (kc == 0) {
      const float rg = fast_sigmoid(gr0 + gbr + pr);
      const float zg = fast_sigmoid(gz0 + gbz + pz);
      const float nn = fast_tanh(gn0 + rg * (pn + gbn));
      const float hn = (1.f - zg) * nn + zg * hprev;
      hprev = hn;
      sm[(size_t)((t + 1) & 1) * H + j] = hn;   // LDS hand-off
      hall[(size_t)t * H + j] = hn;             // history for BN (fire-and-forget)
    }
    __syncthreads();    // separates step-t writes from step-(t+1) reads
  }
}

// ================= phase 2b: persistent cross-WG scans (e3, e2, router) ===========
// 576-thread blocks: waves 0-7 = R5-proven compute (poll -> stage -> barrier ->
// compute); wave 8 = prefetch wave that pre-touches row t+2 AFTER the barrier
// (pulls poisoned lines into the XCD L2 so the producers' partial-line stores
// merge without a memory-side allocate fetch on the visibility chain).
struct ScanArgs {
  const float* GI;
  const float* rwhh; const float* rbhh; float* hs;
  const float* w2; const float* b2; float* ha2;
  const float* w3; const float* b3; float* ha3;
  int* cnt;
};

template<int H, int OPW>
__device__ void expert_scan(const float* __restrict__ GIe, const float* __restrict__ whh,
                            const float* __restrict__ bhh, float* __restrict__ hall,
                            float* __restrict__ sm, int wg)
{
  constexpr int KCN = 512 / OPW;        // e3: 32, e2: 16
  constexpr int CHUNK = H / KCN;        // 16, 16
  constexpr int NF4 = CHUNK / 4;        // 4, 4
  constexpr int PSTR = H / 64;          // prefetch stride (floats): 8, 4
  const int tid = threadIdx.x;
  const bool act = (tid < 512);
  const int lane = tid & 63;
  const int j = (tid / KCN) & (OPW - 1);
  const int kc = tid & (KCN - 1);
  const int jg = wg * OPW + j;

  float4 wr[NF4], wz[NF4], wn[NF4];
  float gbr = 0.f, gbz = 0.f, gbn = 0.f, hprev = 0.f;
  float gAr = 0.f, gAz = 0.f, gAn = 0.f, gBr = 0.f, gBz = 0.f, gBn = 0.f;
  if (act) {
#pragma unroll
    for (int i4 = 0; i4 < NF4; ++i4) {
      const int kk = kc * CHUNK + ((i4 + kc) & (NF4 - 1)) * 4;   // bank-rotated
      wr[i4] = *(const float4*)(whh + (size_t)jg * H + kk);
      wz[i4] = *(const float4*)(whh + (size_t)(H + jg) * H + kk);
      wn[i4] = *(const float4*)(whh + (size_t)(2*H + jg) * H + kk);
    }
    if (kc == 0) { gbr = bhh[jg]; gbz = bhh[H + jg]; gbn = bhh[2*H + jg]; }
    { const float* g = GIe + (size_t)kc * RTOT;          // gi block 0
      gAr = g[jg]; gAz = g[H + jg]; gAn = g[2*H + jg]; }
    { const float* g = GIe + (size_t)(KCN + kc) * RTOT;  // gi block 1
      gBr = g[jg]; gBz = g[H + jg]; gBn = g[2*H + jg]; }
  } else {
    // warm rows 0,1 before the loop (one-time drain at first barrier)
    const int l = tid - 512;
    volatile const float* p0 = (volatile const float*)(hall + (size_t)0 * H + l * PSTR);
    volatile const float* p1 = (volatile const float*)(hall + (size_t)1 * H + l * PSTR);
    float d0 = *p0, d1 = *p1;
    asm volatile("" :: "v"(d0), "v"(d1));
  }

  for (int t = 0; t < NTOK; ++t) {
    if (act) {
      // mass-parallel scalar poison-poll (R0/R5-proven detect structure)
      float val = 0.f;
      if (tid < H && t > 0) {
        const volatile float* p = (const volatile float*)(hall + (size_t)(t - 1) * H + tid);
        val = *p;
        while (is_poison(val)) val = *p;
      }
      if (tid < H) sm[(size_t)(t & 1) * H + tid] = val;
    }
    __syncthreads();                      // single barrier per step (parity-safe)
    if (act) {
      const int m = t & (KCN - 1);
      if (m == 0 && t > 0) {              // rotate gi; prefetch issued just after
        gAr = gBr; gAz = gBz; gAn = gBn;  // the barrier -> ages a full step
        const int nb = t + KCN;
        if (nb + kc < NTOK) {
          const float* g = GIe + (size_t)(nb + kc) * RTOT;
          gBr = g[jg]; gBz = g[H + jg]; gBn = g[2*H + jg];
        }
      }
      const int src = (lane & ~(KCN - 1)) | m;
      const float gr0 = __shfl(gAr, src);
      const float gz0 = __shfl(gAz, src);
      const float gn0 = __shfl(gAn, src);
      const float* hbuf = sm + (size_t)(t & 1) * H;
      float pr = 0.f, pz = 0.f, pn = 0.f;
#pragma unroll
      for (int i4 = 0; i4 < NF4; ++i4) {
        const float4 h4 = *(const float4*)(hbuf + kc * CHUNK + ((i4 + kc) & (NF4 - 1)) * 4);
        pr = fmaf(wr[i4].x, h4.x, pr); pr = fmaf(wr[i4].y, h4.y, pr);
        pr = fmaf(wr[i4].z, h4.z, pr); pr = fmaf(wr[i4].w, h4.w, pr);
        pz = fmaf(wz[i4].x, h4.x, pz); pz = fmaf(wz[i4].y, h4.y, pz);
        pz = fmaf(wz[i4].z, h4.z, pz); pz = fmaf(wz[i4].w, h4.w, pz);
        pn = fmaf(wn[i4].x, h4.x, pn); pn = fmaf(wn[i4].y, h4.y, pn);
        pn = fmaf(wn[i4].w, h4.w, pn); pn = fmaf(wn[i4].z, h4.z, pn);
      }
#pragma unroll
      for (int off = KCN / 2; off; off >>= 1) {
        pr += __shfl_down(pr, off); pz += __shfl_down(pz, off); pn += __shfl_down(pn, off);
      }
      if (kc == 0) {
        const float rg = fast_sigmoid(gr0 + gbr + pr);
        const float zg = fast_sigmoid(gz0 + gbz + pz);
        const float nn = fast_tanh(gn0 + rg * (pn + gbn));
        const float hn = (1.f - zg) * nn + zg * hprev;
        hprev = hn;
        *(volatile float*)(hall + (size_t)t * H + jg) = hn;   // message + history
      }
    } else if (t + 2 < NTOK) {
      // prefetch wave: pre-touch row t+2 (issued after barrier -> drained next
      // barrier at age ~1 step -> off the critical path)
      const int l = tid - 512;
      volatile const float* p = (volatile const float*)(hall + (size_t)(t + 2) * H + l * PSTR);
      float d = *p;
      asm volatile("" :: "v"(d));
    }
  }
}

// router scan: 8 WGs, 512 active threads + wave 8 barrier-filler.
__device__ void router_scan(const float* __restrict__ GI, const float* __restrict__ whh,
                            const float* __restrict__ bhh, float* __restrict__ hs,
                            float* __restrict__ sm, int wg)
{
  float* hsmB = sm;              // 16 rows x 260 (k-major per batch row, pad 4)
  float* pbuf = sm + 16 * 260;   // 16*32*3 partials
  const int tid = threadIdx.x;
  const bool act = (tid < 512);
  const int j = (tid >> 4) & 31, kc = tid & 15;
  const int jg = wg * 32 + j;
  float4 wr4[4], wz4[4], wn4[4];
  if (act) {
#pragma unroll
    for (int i4 = 0; i4 < 4; ++i4) {
      const int kk = kc * 16 + ((i4 + kc) & 3) * 4;
      wr4[i4] = *(const float4*)(whh + (size_t)jg * 256 + kk);
      wz4[i4] = *(const float4*)(whh + (size_t)(256 + jg) * 256 + kk);
      wn4[i4] = *(const float4*)(whh + (size_t)(512 + jg) * 256 + kk);
    }
  }
  const int b2 = (tid >> 5) & 15, j2 = tid & 31;       // gate-stage identity
  const int jg2 = wg * 32 + j2;
  float gbr = 0.f, gbz = 0.f, gbn = 0.f;
  float gr0 = 0.f, gz0 = 0.f, gn0 = 0.f, gr1 = 0.f, gz1 = 0.f, gn1 = 0.f;
  if (act) {
    gbr = bhh[jg2]; gbz = bhh[256 + jg2]; gbn = bhh[512 + jg2];
    { const float* g = GI + (size_t)b2 * RTOT;        gr0 = g[jg2]; gz0 = g[256 + jg2]; gn0 = g[512 + jg2]; }
    { const float* g = GI + (size_t)(16 + b2) * RTOT; gr1 = g[jg2]; gz1 = g[256 + jg2]; gn1 = g[512 + jg2]; }
  }
  const int pb = (tid >> 5) & 15, pk = (tid & 31) * 8;

  for (int t = 0; t < TT; ++t) {
    float v[8];
    if (act) {
      if (t == 0) {
#pragma unroll
        for (int u = 0; u < 8; ++u) v[u] = 0.f;
      } else {
        const volatile float* q = (const volatile float*)(hs + (size_t)(t - 1) * 4096 + tid * 8);
#pragma unroll
        for (int u = 0; u < 8; ++u) v[u] = q[u];
        bool bad = true;
        while (bad) {
          bad = false;
#pragma unroll
          for (int u = 0; u < 8; ++u)
            if (is_poison(v[u])) { v[u] = q[u]; bad = true; }
        }
      }
    }
    float gr2 = 0.f, gz2 = 0.f, gn2 = 0.f;
    if (act && t + 2 < TT) {
      const float* g = GI + (size_t)((t + 2) * 16 + b2) * RTOT;
      gr2 = g[jg2]; gz2 = g[256 + jg2]; gn2 = g[512 + jg2];
    }
    __syncthreads();
    if (act) {
      *(float4*)(hsmB + pb * 260 + pk)     = make_float4(v[0], v[1], v[2], v[3]);
      *(float4*)(hsmB + pb * 260 + pk + 4) = make_float4(v[4], v[5], v[6], v[7]);
    }
    __syncthreads();
    if (act) {
      float ar[16], az[16], an[16];
#pragma unroll
      for (int b = 0; b < 16; ++b) { ar[b] = 0.f; az[b] = 0.f; an[b] = 0.f; }
#pragma unroll
      for (int i4 = 0; i4 < 4; ++i4) {
        const int col = kc * 16 + ((i4 + kc) & 3) * 4;
#pragma unroll
        for (int b = 0; b < 16; ++b) {
          const float4 h4 = *(const float4*)(hsmB + b * 260 + col);
          ar[b] = fmaf(wr4[i4].x, h4.x, ar[b]); ar[b] = fmaf(wr4[i4].y, h4.y, ar[b]);
          ar[b] = fmaf(wr4[i4].z, h4.z, ar[b]); ar[b] = fmaf(wr4[i4].w, h4.w, ar[b]);
          az[b] = fmaf(wz4[i4].x, h4.x, az[b]); az[b] = fmaf(wz4[i4].y, h4.y, az[b]);
          az[b] = fmaf(wz4[i4].z, h4.z, az[b]); az[b] = fmaf(wz4[i4].w, h4.w, az[b]);
          an[b] = fmaf(wn4[i4].x, h4.x, an[b]); an[b] = fmaf(wn4[i4].y, h4.y, an[b]);
          an[b] = fmaf(wn4[i4].z, h4.z, an[b]); an[b] = fmaf(wn4[i4].w, h4.w, an[b]);
        }
      }
#pragma unroll
      for (int off = 8; off; off >>= 1) {
#pragma unroll
        for (int b = 0; b < 16; ++b) {
          ar[b] += __shfl_down(ar[b], off);
          az[b] += __shfl_down(az[b], off);
          an[b] += __shfl_down(an[b], off);
        }
      }
      if (kc == 0) {
#pragma unroll
        for (int b = 0; b < 16; ++b) {
          pbuf[(b * 32 + j) * 3 + 0] = ar[b];
          pbuf[(b * 32 + j) * 3 + 1] = az[b];
          pbuf[(b * 32 + j) * 3 + 2] = an[b];
        }
      }
    }
    __syncthreads();
    if (act) {
      const float pr = pbuf[(b2 * 32 + j2) * 3 + 0];
      const float pz = pbuf[(b2 * 32 + j2) * 3 + 1];
      const float pn = pbuf[(b2 * 32 + j2) * 3 + 2];
      const float hprev = hsmB[b2 * 260 + jg2];
      const float rg = 1.f / (1.f + expf(-(gr0 + gbr + pr)));
      const float zg = 1.f / (1.f + expf(-(gz0 + gbz + pz)));
      const float nn = tanhf(gn0 + rg * (pn + gbn));
      const float hn = (1.f - zg) * nn + zg * hprev;
      *(volatile float*)(hs + (size_t)t * 4096 + b2 * 256 + jg2) = hn;
      gr0 = gr1; gz0 = gz1; gn0 = gn1;
      gr1 = gr2; gz1 = gz2; gn1 = gn2;
    }
  }
}

__global__ __launch_bounds__(576, 1) void scan_kernel(ScanArgs A)
{
  __shared__ __attribute__((aligned(16))) float sm[16 * 260 + 1536];
  __shared__ int role_s[2];
  if (threadIdx.x == 0) {
    unsigned x;
    asm volatile("s_getreg_b32 %0, hwreg(HW_REG_XCC_ID)" : "=s"(x));
    const int xcd = (int)(x & 7u);
    role_s[0] = xcd;
    role_s[1] = atomicAdd(A.cnt + xcd, 1);  // device-scope, claim rank within my XCD
  }
  __syncthreads();
  const int xcd = role_s[0], r = role_s[1];
  if (xcd == 0)      { if (r < 32) expert_scan<512, 16>(A.GI + E3OFF, A.w3, A.b3, A.ha3, sm, r); }
  else if (xcd == 1) { if (r < 8)  router_scan(A.GI, A.rwhh, A.rbhh, A.hs, sm, r); }
  else if (xcd == 2) { if (r < 8)  expert_scan<256, 32>(A.GI + E2OFF, A.w2, A.b2, A.ha2, sm, r); }
  // e1 runs in its own single-WG kernel; all other WGs exit immediately
}

// ================= phase 3a: router head, softmax, eul/task atomics =================
__global__ __launch_bounds__(256) void router_out_kernel(
    const float* __restrict__ hs, const float* __restrict__ ow, const float* __restrict__ ob,
    const int* __restrict__ tids, float* __restrict__ raw_out,
    float* __restrict__ tsum, float* __restrict__ tcnt)
{
  const int tid = threadIdx.x;
  const int lane = tid & 63, w = tid >> 6;
  const int n = blockIdx.x * 4 + w;
  float s0 = 0.f, s1 = 0.f, s2 = 0.f, s3 = 0.f;
#pragma unroll
  for (int q = 0; q < 4; ++q) {
    const int jj = lane + q * 64;
    float h = hs[(size_t)n * 256 + jj];
    h = h > 0.f ? h : 0.f;
    s0 = fmaf(h, ow[jj], s0);
    s1 = fmaf(h, ow[256 + jj], s1);
    s2 = fmaf(h, ow[512 + jj], s2);
    s3 = fmaf(h, ow[768 + jj], s3);
  }
  for (int off = 32; off; off >>= 1) {
    s0 += __shfl_xor(s0, off); s1 += __shfl_xor(s1, off);
    s2 += __shfl_xor(s2, off); s3 += __shfl_xor(s3, off);
  }
  if (lane == 0) {
    const float l0 = s0 + ob[0], l1 = s1 + ob[1], l2 = s2 + ob[2], l3 = s3 + ob[3];
    const float m = fmaxf(fmaxf(l0, l1), fmaxf(l2, l3));
    const float e0 = expf(l0 - m), e1 = expf(l1 - m), e2 = expf(l2 - m), e3 = expf(l3 - m);
    const float inv = 1.f / (e0 + e1 + e2 + e3);
    float4 rv; rv.x = e0 * inv; rv.y = e1 * inv; rv.z = e2 * inv; rv.w = e3 * inv;
    *(float4*)(raw_out + (size_t)n * 4) = rv;
    const float eul = rv.y * 128.f + rv.z * 256.f + rv.w * 512.f;
    const int tk = tids[n];
    atomicAdd(&tsum[tk], eul);
    atomicAdd(&tcnt[tk], 1.f);
  }
}

// ================= phase 3b: BN stats per column =================
__global__ __launch_bounds__(256) void bn_stats_kernel(
    const float* __restrict__ h1, const float* __restrict__ h2, const float* __restrict__ h3,
    float* __restrict__ mu, float* __restrict__ rstd)
{
  const int c = blockIdx.x;
  const float* hp; int He, hc;
  if (c < 128)      { hp = h1; He = 128; hc = c; }
  else if (c < 384) { hp = h2; He = 256; hc = c - 128; }
  else              { hp = h3; He = 512; hc = c - 384; }
  float s = 0.f, s2 = 0.f;
  for (int r = threadIdx.x; r < NTOK; r += 256) {
    const float v = hp[(size_t)r * He + hc];
    s += v; s2 = fmaf(v, v, s2);
  }
  for (int off = 32; off; off >>= 1) { s += __shfl_xor(s, off); s2 += __shfl_xor(s2, off); }
  __shared__ float red[8];
  const int lane = threadIdx.x & 63, w = threadIdx.x >> 6;
  if (lane == 0) { red[w] = s; red[4 + w] = s2; }
  __syncthreads();
  if (threadIdx.x == 0) {
    const float S = red[0] + red[1] + red[2] + red[3];
    const float S2 = red[4] + red[5] + red[6] + red[7];
    const float m = S * (1.f / 4096.f);
    float v = S2 * (1.f / 4096.f) - m * m;
    v = v > 0.f ? v : 0.f;
    mu[c] = m;
    rstd[c] = 1.f / sqrtf(v + 1e-5f);
  }
}

// ================= phase 3c: A' = gate * relu(bn(h)); plus task losses =================
__global__ __launch_bounds__(256) void aprime_kernel(
    const float* __restrict__ h1, const float* __restrict__ h2, const float* __restrict__ h3,
    const float* __restrict__ g1, const float* __restrict__ be1,
    const float* __restrict__ g2, const float* __restrict__ be2,
    const float* __restrict__ g3, const float* __restrict__ be3,
    const float* __restrict__ mu, const float* __restrict__ rstd,
    const float* __restrict__ raw, float* __restrict__ Ap,
    const float* __restrict__ tsum, const float* __restrict__ tcnt, float* __restrict__ tl_out)
{
  if (blockIdx.x == 4096) {
    if (threadIdx.x < 4) tl_out[threadIdx.x] = tsum[threadIdx.x] / tcnt[threadIdx.x];
    return;
  }
  const int n = blockIdx.x;
  for (int c = threadIdx.x; c < 896; c += 256) {
    const float* hp; const float* gg; const float* bb; int He, hc, e;
    if (c < 128)      { hp = h1; gg = g1; bb = be1; He = 128; hc = c;       e = 1; }
    else if (c < 384) { hp = h2; gg = g2; bb = be2; He = 256; hc = c - 128; e = 2; }
    else              { hp = h3; gg = g3; bb = be3; He = 512; hc = c - 384; e = 3; }
    const float h = hp[(size_t)n * He + hc];
    float v = (h - mu[c]) * rstd[c] * gg[hc] + bb[hc];
    v = v > 0.f ? v : 0.f;
    Ap[(size_t)n * 896 + c] = raw[(size_t)n * 4 + e] * v;
  }
}

// ================= phase 4: out = A' @ OWc^T + gated biases + g0*x =================
__global__ __launch_bounds__(256) void out_gemm_kernel(
    const float* __restrict__ Ap,
    const float* __restrict__ ow1, const float* __restrict__ ow2, const float* __restrict__ ow3,
    const float* __restrict__ ob1, const float* __restrict__ ob2, const float* __restrict__ ob3,
    const float* __restrict__ X, const float* __restrict__ raw, float* __restrict__ out)
{
  __shared__ float At[32*64];
  __shared__ float Bt[32*64];
  const int n0 = blockIdx.x * 64;
  const int d0 = blockIdx.y * 64;
  const int tid = threadIdx.x;
  const int lm = tid & 63, lk4 = tid >> 6;
  const int tx = tid & 15, ty = tid >> 4;
  float acc[4][4];
#pragma unroll
  for (int i = 0; i < 4; ++i)
#pragma unroll
    for (int q = 0; q < 4; ++q) acc[i][q] = 0.f;

  for (int kb = 0; kb < 896; kb += 32) {
    const float* W; int He, ko;
    if (kb < 128)      { W = ow1; He = 128; ko = 0; }
    else if (kb < 384) { W = ow2; He = 256; ko = 128; }
    else               { W = ow3; He = 512; ko = 384; }
    const float4 a0 = *(const float4*)(Ap + (size_t)(n0+lm)*896 + kb + lk4*8);
    const float4 a1 = *(const float4*)(Ap + (size_t)(n0+lm)*896 + kb + lk4*8 + 4);
    const float4 c0 = *(const float4*)(W + (size_t)(d0+lm)*He + (kb - ko) + lk4*8);
    const float4 c1 = *(const float4*)(W + (size_t)(d0+lm)*He + (kb - ko) + lk4*8 + 4);
    __syncthreads();
    At[(lk4*8+0)*64+lm]=a0.x; At[(lk4*8+1)*64+lm]=a0.y; At[(lk4*8+2)*64+lm]=a0.z; At[(lk4*8+3)*64+lm]=a0.w;
    At[(lk4*8+4)*64+lm]=a1.x; At[(lk4*8+5)*64+lm]=a1.y; At[(lk4*8+6)*64+lm]=a1.z; At[(lk4*8+7)*64+lm]=a1.w;
    Bt[(lk4*8+0)*64+lm]=c0.x; Bt[(lk4*8+1)*64+lm]=c0.y; Bt[(lk4*8+2)*64+lm]=c0.z; Bt[(lk4*8+3)*64+lm]=c0.w;
    Bt[(lk4*8+4)*64+lm]=c1.x; Bt[(lk4*8+5)*64+lm]=c1.y; Bt[(lk4*8+6)*64+lm]=c1.z; Bt[(lk4*8+7)*64+lm]=c1.w;
    __syncthreads();
#pragma unroll
    for (int k = 0; k < 32; ++k) {
      const float4 av = *(const float4*)&At[k*64 + ty*4];
      const float4 bv = *(const float4*)&Bt[k*64 + tx*4];
      acc[0][0]=fmaf(av.x,bv.x,acc[0][0]); acc[0][1]=fmaf(av.x,bv.y,acc[0][1]); acc[0][2]=fmaf(av.x,bv.z,acc[0][2]); acc[0][3]=fmaf(av.x,bv.w,acc[0][3]);
      acc[1][0]=fmaf(av.y,bv.x,acc[1][0]); acc[1][1]=fmaf(av.y,bv.y,acc[1][1]); acc[1][2]=fmaf(av.y,bv.z,acc[1][2]); acc[1][3]=fmaf(av.y,bv.w,acc[1][3]);
      acc[2][0]=fmaf(av.z,bv.x,acc[2][0]); acc[2][1]=fmaf(av.z,bv.y,acc[2][1]); acc[2][2]=fmaf(av.z,bv.z,acc[2][2]); acc[2][3]=fmaf(av.z,bv.w,acc[2][3]);
      acc[3][0]=fmaf(av.w,bv.x,acc[3][0]); acc[3][1]=fmaf(av.w,bv.y,acc[3][1]); acc[3][2]=fmaf(av.w,bv.z,acc[3][2]); acc[3][3]=fmaf(av.w,bv.w,acc[3][3]);
    }
  }
#pragma unroll
  for (int i = 0; i < 4; ++i) {
    const int n = n0 + ty * 4 + i;
    const float4 g  = *(const float4*)(raw + (size_t)n * 4);
    const float4 xv = *(const float4*)(X + (size_t)n * 512 + d0 + tx * 4);
    const float4 o1 = *(const float4*)(ob1 + d0 + tx * 4);
    const float4 o2 = *(const float4*)(ob2 + d0 + tx * 4);
    const float4 o3 = *(const float4*)(ob3 + d0 + tx * 4);
    float4 o;
    o.x = acc[i][0] + g.x*xv.x + g.y*o1.x + g.z*o2.x + g.w*o3.x;
    o.y = acc[i][1] + g.x*xv.y + g.y*o1.y + g.z*o2.y + g.w*o3.y;
    o.z = acc[i][2] + g.x*xv.z + g.y*o1.z + g.z*o2.z + g.w*o3.z;
    o.w = acc[i][3] + g.x*xv.w + g.y*o1.w + g.z*o2.w + g.w*o3.w;
    *(float4*)(out + (size_t)n * 512 + d0 + tx * 4) = o;
  }
}

// ================= host =================
extern "C" void kernel_launch(void* const* d_in, const int* in_sizes, int n_in,
                              void* d_out, int out_size, void* d_ws, size_t ws_size,
                              hipStream_t stream) {
  const float* x    = (const float*)d_in[0];
  const int*   tids = (const int*)d_in[1];
  const float* rwih = (const float*)d_in[2];
  const float* rwhh = (const float*)d_in[3];
  const float* rbih = (const float*)d_in[4];
  const float* rbhh = (const float*)d_in[5];
  const float* row  = (const float*)d_in[6];
  const float* rob  = (const float*)d_in[7];
  const float* w1ih = (const float*)d_in[8];
  const float* w1hh = (const float*)d_in[9];
  const float* b1ih = (const float*)d_in[10];
  const float* b1hh = (const float*)d_in[11];
  const float* bn1g = (const float*)d_in[12];
  const float* bn1b = (const float*)d_in[13];
  const float* ow1  = (const float*)d_in[14];
  const float* ob1  = (const float*)d_in[15];
  const float* w2ih = (const float*)d_in[16];
  const float* w2hh = (const float*)d_in[17];
  const float* b2ih = (const float*)d_in[18];
  const float* b2hh = (const float*)d_in[19];
  const float* bn2g = (const float*)d_in[20];
  const float* bn2b = (const float*)d_in[21];
  const float* ow2  = (const float*)d_in[22];
  const float* ob2  = (const float*)d_in[23];
  const float* w3ih = (const float*)d_in[24];
  const float* w3hh = (const float*)d_in[25];
  const float* b3ih = (const float*)d_in[26];
  const float* b3hh = (const float*)d_in[27];
  const float* bn3g = (const float*)d_in[28];
  const float* bn3b = (const float*)d_in[29];
  const float* ow3  = (const float*)d_in[30];
  const float* ob3  = (const float*)d_in[31];

  char* ws = (char*)d_ws;
  float* tsum = (float*)(ws + OFF_TSUM);
  float* tcnt = (float*)(ws + OFF_TCNT);
  int*   cnt  = (int*)(ws + OFF_CNT);
  float* GI   = (float*)(ws + OFF_GI);
  float* hs   = (float*)(ws + OFF_HS);
  float* ha3  = (float*)(ws + OFF_HA3);
  float* ha2  = (float*)(ws + OFF_HA2);
  float* ha1  = (float*)(ws + OFF_HA1);
  float* Ap   = (float*)(ws + OFF_AP);
  float* mu   = (float*)(ws + OFF_MU);
  float* rstd = (float*)(ws + OFF_RSTD);

  float* outp = (float*)d_out;
  float* rawp = outp + (size_t)NTOK * DD;
  float* tlp  = rawp + (size_t)NTOK * 4;

  // zero claim counters + task accumulators; self-poison the h-history exchange
  // buffers (value==0xAAAAAAAA is the "not ready" sentinel the scan polls against)
  hipMemsetAsync(ws, 0, ZBYTES, stream);
  hipMemsetAsync(ws + OFF_HS, 0xAA, POISON_BYTES, stream);

  // phase 1: input projections for router + all experts
  gemm1_kernel<<<dim3(64, 54), 256, 0, stream>>>(x, rwih, w1ih, w2ih, w3ih,
                                                 rbih, b1ih, b2ih, b3ih, GI);

  // phase 2a: e1 single-WG LDS-only scan (separate dispatch = per-chain timing)
  e1_scan_kernel<<<dim3(1), dim3(1024), 0, stream>>>(GI + E1OFF, w1hh, b1hh, ha1);

  // phase 2b: XCD-claimed persistent scans (e3 + router + e2, prefetch wave)
  ScanArgs sa;
  sa.GI = GI; sa.rwhh = rwhh; sa.rbhh = rbhh; sa.hs = hs;
  sa.w2 = w2hh; sa.b2 = b2hh; sa.ha2 = ha2;
  sa.w3 = w3hh; sa.b3 = b3hh; sa.ha3 = ha3;
  sa.cnt = cnt;
  scan_kernel<<<dim3(320), dim3(576), 0, stream>>>(sa);

  // phase 3: router head + task-loss atomics; BN stats; A' build (+ task losses)
  router_out_kernel<<<dim3(1024), 256, 0, stream>>>(hs, row, rob, tids, rawp, tsum, tcnt);
  bn_stats_kernel<<<dim3(896), 256, 0, stream>>>(ha1, ha2, ha3, mu, rstd);
  aprime_kernel<<<dim3(4097), 256, 0, stream>>>(ha1, ha2, ha3, bn1g, bn1b, bn2g, bn2b,
                                                bn3g, bn3b, mu, rstd, rawp, Ap,
                                                tsum, tcnt, tlp);

  // phase 4: gated expert-output GEMM + identity expert + gated biases
  out_gemm_kernel<<<dim3(64, 8), 256, 0, stream>>>(Ap, ow1, ow2, ow3, ob1, ob2, ob3,
                                                   x, rawp, outp);
}

// Round 7
// 6664.668 us; speedup vs baseline: 1.6559x; 1.6559x over previous
//
#include <hip/hip_runtime.h>
#include <math.h>

// ---------------- problem constants ----------------
constexpr int TT = 256, BB = 16, DD = 512;
constexpr int NTOK = 4096;                 // T*B
constexpr int RTOT = 3456;                 // 768 + 384 + 768 + 1536
constexpr int E1OFF = 768, E2OFF = 1152, E3OFF = 1920;

// ---------------- workspace layout (bytes) ----------------
constexpr size_t OFF_TSUM = 0;                                   // 4 f
constexpr size_t OFF_TCNT = 16;                                  // 4 f
constexpr size_t OFF_CNT  = 32;                                  // 8 ints (XCD claim counters)
constexpr size_t ZBYTES   = 64;
constexpr size_t OFF_GI   = 4096;
constexpr size_t OFF_HS   = OFF_GI  + (size_t)NTOK*RTOT*4;       // router h history (poll target)
constexpr size_t OFF_HA3  = OFF_HS  + (size_t)NTOK*256*4;
constexpr size_t OFF_HA2  = OFF_HA3 + (size_t)NTOK*512*4;
constexpr size_t OFF_HA1  = OFF_HA2 + (size_t)NTOK*256*4;
constexpr size_t OFF_AP   = OFF_HA1 + (size_t)NTOK*128*4;
constexpr size_t OFF_MU   = OFF_AP  + (size_t)NTOK*896*4;
constexpr size_t OFF_RSTD = OFF_MU  + 896*4;
constexpr size_t POISON_BYTES = (size_t)NTOK*(256+512+256+128)*4;  // HS..HA1 contiguous

__device__ __forceinline__ bool is_poison(float v) {
  return __float_as_uint(v) == 0xAAAAAAAAu;
}

// fast, clamped activations (~2ulp; validated in R5: absmax unchanged)
__device__ __forceinline__ float fast_sigmoid(float x) {
  const float xc = fminf(fmaxf(x, -30.f), 30.f);
  return __fdividef(1.f, 1.f + __expf(-xc));
}
__device__ __forceinline__ float fast_tanh(float x) {
  const float xc = fminf(fmaxf(x, -15.f), 15.f);
  const float e = __expf(-2.f * xc);
  return (1.f - e) * __fdividef(1.f, 1.f + e);
}

// ================= phase 1: gi = x @ Wih^T + b_ih (all 3456 rows) =================
__global__ __launch_bounds__(256) void gemm1_kernel(
    const float* __restrict__ X,
    const float* __restrict__ wR, const float* __restrict__ w1,
    const float* __restrict__ w2, const float* __restrict__ w3,
    const float* __restrict__ bR, const float* __restrict__ b1,
    const float* __restrict__ b2, const float* __restrict__ b3,
    float* __restrict__ GI)
{
  __shared__ float At[32*64];
  __shared__ float Bt[32*64];
  const int n0 = blockIdx.x * 64;
  const int r0 = blockIdx.y * 64;
  const float* W; const float* bias; int rs;
  if (r0 < 768)       { W = wR; bias = bR; rs = 0; }
  else if (r0 < 1152) { W = w1; bias = b1; rs = 768; }
  else if (r0 < 1920) { W = w2; bias = b2; rs = 1152; }
  else                { W = w3; bias = b3; rs = 1920; }
  const int lr0 = r0 - rs;
  const int tid = threadIdx.x;
  const int lm = tid & 63, lk4 = tid >> 6;
  const int tx = tid & 15, ty = tid >> 4;
  float acc[4][4];
#pragma unroll
  for (int i = 0; i < 4; ++i)
#pragma unroll
    for (int q = 0; q < 4; ++q) acc[i][q] = 0.f;

  for (int kb = 0; kb < 512; kb += 32) {
    const float4 a0 = *(const float4*)(X + (size_t)(n0+lm)*512 + kb + lk4*8);
    const float4 a1 = *(const float4*)(X + (size_t)(n0+lm)*512 + kb + lk4*8 + 4);
    const float4 c0 = *(const float4*)(W + (size_t)(lr0+lm)*512 + kb + lk4*8);
    const float4 c1 = *(const float4*)(W + (size_t)(lr0+lm)*512 + kb + lk4*8 + 4);
    __syncthreads();
    At[(lk4*8+0)*64+lm]=a0.x; At[(lk4*8+1)*64+lm]=a0.y; At[(lk4*8+2)*64+lm]=a0.z; At[(lk4*8+3)*64+lm]=a0.w;
    At[(lk4*8+4)*64+lm]=a1.x; At[(lk4*8+5)*64+lm]=a1.y; At[(lk4*8+6)*64+lm]=a1.z; At[(lk4*8+7)*64+lm]=a1.w;
    Bt[(lk4*8+0)*64+lm]=c0.x; Bt[(lk4*8+1)*64+lm]=c0.y; Bt[(lk4*8+2)*64+lm]=c0.z; Bt[(lk4*8+3)*64+lm]=c0.w;
    Bt[(lk4*8+4)*64+lm]=c1.x; Bt[(lk4*8+5)*64+lm]=c1.y; Bt[(lk4*8+6)*64+lm]=c1.z; Bt[(lk4*8+7)*64+lm]=c1.w;
    __syncthreads();
#pragma unroll
    for (int k = 0; k < 32; ++k) {
      const float4 av = *(const float4*)&At[k*64 + ty*4];
      const float4 bv = *(const float4*)&Bt[k*64 + tx*4];
      acc[0][0]=fmaf(av.x,bv.x,acc[0][0]); acc[0][1]=fmaf(av.x,bv.y,acc[0][1]); acc[0][2]=fmaf(av.x,bv.z,acc[0][2]); acc[0][3]=fmaf(av.x,bv.w,acc[0][3]);
      acc[1][0]=fmaf(av.y,bv.x,acc[1][0]); acc[1][1]=fmaf(av.y,bv.y,acc[1][1]); acc[1][2]=fmaf(av.y,bv.z,acc[1][2]); acc[1][3]=fmaf(av.y,bv.w,acc[1][3]);
      acc[2][0]=fmaf(av.z,bv.x,acc[2][0]); acc[2][1]=fmaf(av.z,bv.y,acc[2][1]); acc[2][2]=fmaf(av.z,bv.z,acc[2][2]); acc[2][3]=fmaf(av.z,bv.w,acc[2][3]);
      acc[3][0]=fmaf(av.w,bv.x,acc[3][0]); acc[3][1]=fmaf(av.w,bv.y,acc[3][1]); acc[3][2]=fmaf(av.w,bv.z,acc[3][2]); acc[3][3]=fmaf(av.w,bv.w,acc[3][3]);
    }
  }
  const float4 bb = *(const float4*)(bias + lr0 + tx*4);
#pragma unroll
  for (int i = 0; i < 4; ++i) {
    float4 o;
    o.x = acc[i][0] + bb.x; o.y = acc[i][1] + bb.y; o.z = acc[i][2] + bb.z; o.w = acc[i][3] + bb.w;
    *(float4*)(GI + (size_t)(n0+ty*4+i)*RTOT + r0 + tx*4) = o;
  }
}

// ================= phase 2: persistent scans (XCD-claimed roles) =================
// R6 DIAGNOSTIC: single-WG LDS-only e1 chain also runs ~1030ns/step -> the
// binding constraint is the per-CU LDS pipe (ds_read_b128 ~12cy + ds_bpermute
// shuffles ~6cy, cost = waves x ds-instr/wave), NOT the L2 exchange.
// FIX: e3/e2 use 4 ACTIVE waves (256 threads) instead of 8 -> per-CU LDS ops
// ~halve (e3: 1104 -> ~670 cy/step); idle waves are barrier-companions only.
struct ScanArgs {
  const float* GI;
  const float* rwhh; const float* rbhh; float* hs;
  const float* w1; const float* b1; float* ha1;
  const float* w2; const float* b2; float* ha2;
  const float* w3; const float* b3; float* ha3;
  int* cnt;
};

// -------- 4-wave expert scan (256 active threads; e3: H=512 OPW=16, e2: H=256 OPW=16)
template<int H, int OPW>
__device__ void expert_scan4w(const float* __restrict__ GIe, const float* __restrict__ whh,
                              const float* __restrict__ bhh, float* __restrict__ hall,
                              float* __restrict__ sm, int wg)
{
  constexpr int ACT = 256;
  constexpr int KCN = ACT / OPW;        // 16
  constexpr int C   = H / KCN;          // 32 (e3), 16 (e2)
  constexpr int NF4 = C / 4;            // 8, 4
  constexpr int PP  = H / ACT;          // floats polled/staged per thread: 2, 1
  const int tid = threadIdx.x;
  if (tid >= ACT) {                     // idle waves: match the 1 barrier/step
    for (int t = 0; t < NTOK; ++t) __syncthreads();
    return;
  }
  const int j = tid / KCN, kc = tid % KCN;
  const int jg = wg * OPW + j;
  const int lane = tid & 63;

  // NOTE: e3 needs 3*NF4=24 float4 = 96 VGPR of weights. If the compiler sinks
  // these (VGPR_Count ~110 instead of ~180+), that is the next diagnostic.
  float4 wr[NF4], wz[NF4], wn[NF4];
#pragma unroll
  for (int i4 = 0; i4 < NF4; ++i4) {
    const int kk = kc * C + ((i4 + kc) & (NF4 - 1)) * 4;   // bank-rotated
    wr[i4] = *(const float4*)(whh + (size_t)jg * H + kk);
    wz[i4] = *(const float4*)(whh + (size_t)(H + jg) * H + kk);
    wn[i4] = *(const float4*)(whh + (size_t)(2*H + jg) * H + kk);
  }
  float gbr = 0.f, gbz = 0.f, gbn = 0.f, hprev = 0.f;
  if (kc == 0) { gbr = bhh[jg]; gbz = bhh[H + jg]; gbn = bhh[2*H + jg]; }

  // gi lane-held double buffer: lane kc holds gi(t) for t == block*KCN + kc
  float gAr, gAz, gAn, gBr, gBz, gBn;
  { const float* g = GIe + (size_t)kc * RTOT;
    gAr = g[jg]; gAz = g[H + jg]; gAn = g[2*H + jg]; }
  { const float* g = GIe + (size_t)(KCN + kc) * RTOT;
    gBr = g[jg]; gBz = g[H + jg]; gBn = g[2*H + jg]; }

  for (int t = 0; t < NTOK; ++t) {
    // ---- poll h(t-1): PP floats per thread, scalar poison-poll ----
    float v0 = 0.f, v1 = 0.f;
    if (t > 0) {
      const volatile float* p = (const volatile float*)(hall + (size_t)(t - 1) * H + tid * PP);
      v0 = p[0];
      while (is_poison(v0)) v0 = p[0];
      if constexpr (PP == 2) {
        v1 = p[1];
        while (is_poison(v1)) v1 = p[1];
      }
    }
    sm[(size_t)(t & 1) * H + tid * PP] = v0;
    if constexpr (PP == 2) sm[(size_t)(t & 1) * H + tid * PP + 1] = v1;
    __syncthreads();                    // single barrier per step (parity-safe)
    const float* hbuf = sm + (size_t)(t & 1) * H;

    const int m = t & (KCN - 1);
    if (m == 0 && t > 0) {              // rotate gi; issued right after barrier
      gAr = gBr; gAz = gBz; gAn = gBn;
      const int nb = t + KCN;
      if (nb + kc < NTOK) {
        const float* g = GIe + (size_t)(nb + kc) * RTOT;
        gBr = g[jg]; gBz = g[H + jg]; gBn = g[2*H + jg];
      }
    }
    const int src = (lane & ~(KCN - 1)) | m;
    const float gr0 = __shfl(gAr, src);
    const float gz0 = __shfl(gAz, src);
    const float gn0 = __shfl(gAn, src);

    float pr = 0.f, pz = 0.f, pn = 0.f;
#pragma unroll
    for (int i4 = 0; i4 < NF4; ++i4) {
      const float4 h4 = *(const float4*)(hbuf + kc * C + ((i4 + kc) & (NF4 - 1)) * 4);
      pr = fmaf(wr[i4].x, h4.x, pr); pr = fmaf(wr[i4].y, h4.y, pr);
      pr = fmaf(wr[i4].z, h4.z, pr); pr = fmaf(wr[i4].w, h4.w, pr);
      pz = fmaf(wz[i4].x, h4.x, pz); pz = fmaf(wz[i4].y, h4.y, pz);
      pz = fmaf(wz[i4].z, h4.z, pz); pz = fmaf(wz[i4].w, h4.w, pz);
      pn = fmaf(wn[i4].x, h4.x, pn); pn = fmaf(wn[i4].y, h4.y, pn);
      pn = fmaf(wn[i4].z, h4.z, pn); pn = fmaf(wn[i4].w, h4.w, pn);
    }
#pragma unroll
    for (int off = KCN / 2; off; off >>= 1) {
      pr += __shfl_down(pr, off); pz += __shfl_down(pz, off); pn += __shfl_down(pn, off);
    }
    if (kc == 0) {
      const float rg = fast_sigmoid(gr0 + gbr + pr);
      const float zg = fast_sigmoid(gz0 + gbz + pz);
      const float nn = fast_tanh(gn0 + rg * (pn + gbn));
      const float hn = (1.f - zg) * nn + zg * hprev;
      hprev = hn;
      *(volatile float*)(hall + (size_t)t * H + jg) = hn;   // message + history
    }
  }
}

// -------- 512-thread expert scan (e1: H=128, OPW=32, KCN=16, C=8 — R5-proven)
template<int H, int OPW>
__device__ void expert_scan(const float* __restrict__ GIe, const float* __restrict__ whh,
                            const float* __restrict__ bhh, float* __restrict__ hall,
                            float* __restrict__ sm, int wg)
{
  constexpr int KCN = 512 / OPW;
  constexpr int CHUNK = H / KCN;
  constexpr int NF4 = CHUNK / 4;
  const int tid = threadIdx.x;
  const int j = tid / KCN, kc = tid % KCN;
  const int jg = wg * OPW + j;
  const int lane = tid & 63;

  float4 wr[NF4], wz[NF4], wn[NF4];
#pragma unroll
  for (int i4 = 0; i4 < NF4; ++i4) {
    const int kk = kc * CHUNK + ((i4 + kc) & (NF4 - 1)) * 4;
    wr[i4] = *(const float4*)(whh + (size_t)jg * H + kk);
    wz[i4] = *(const float4*)(whh + (size_t)(H + jg) * H + kk);
    wn[i4] = *(const float4*)(whh + (size_t)(2*H + jg) * H + kk);
  }
  float gbr = 0.f, gbz = 0.f, gbn = 0.f, hprev = 0.f;
  if (kc == 0) { gbr = bhh[jg]; gbz = bhh[H + jg]; gbn = bhh[2*H + jg]; }

  float gAr, gAz, gAn, gBr, gBz, gBn;
  { const float* g = GIe + (size_t)kc * RTOT;
    gAr = g[jg]; gAz = g[H + jg]; gAn = g[2*H + jg]; }
  { const float* g = GIe + (size_t)(KCN + kc) * RTOT;
    gBr = g[jg]; gBz = g[H + jg]; gBn = g[2*H + jg]; }

  for (int t = 0; t < NTOK; ++t) {
    float val = 0.f;
    if (tid < H && t > 0) {
      const volatile float* p = (const volatile float*)(hall + (size_t)(t - 1) * H + tid);
      val = *p;
      while (is_poison(val)) val = *p;
    }
    if (tid < H) sm[(size_t)(t & 1) * H + tid] = val;
    __syncthreads();
    const float* hbuf = sm + (size_t)(t & 1) * H;

    const int m = t & (KCN - 1);
    if (m == 0 && t > 0) {
      gAr = gBr; gAz = gBz; gAn = gBn;
      const int nb = t + KCN;
      if (nb + kc < NTOK) {
        const float* g = GIe + (size_t)(nb + kc) * RTOT;
        gBr = g[jg]; gBz = g[H + jg]; gBn = g[2*H + jg];
      }
    }
    const int src = (lane & ~(KCN - 1)) | m;
    const float gr0 = __shfl(gAr, src);
    const float gz0 = __shfl(gAz, src);
    const float gn0 = __shfl(gAn, src);

    float pr = 0.f, pz = 0.f, pn = 0.f;
#pragma unroll
    for (int i4 = 0; i4 < NF4; ++i4) {
      const float4 h4 = *(const float4*)(hbuf + kc * CHUNK + ((i4 + kc) & (NF4 - 1)) * 4);
      pr = fmaf(wr[i4].x, h4.x, pr); pr = fmaf(wr[i4].y, h4.y, pr);
      pr = fmaf(wr[i4].z, h4.z, pr); pr = fmaf(wr[i4].w, h4.w, pr);
      pz = fmaf(wz[i4].x, h4.x, pz); pz = fmaf(wz[i4].y, h4.y, pz);
      pz = fmaf(wz[i4].z, h4.z, pz); pz = fmaf(wz[i4].w, h4.w, pz);
      pn = fmaf(wn[i4].x, h4.x, pn); pn = fmaf(wn[i4].y, h4.y, pn);
      pn = fmaf(wn[i4].w, h4.w, pn); pn = fmaf(wn[i4].z, h4.z, pn);
    }
#pragma unroll
    for (int off = KCN / 2; off; off >>= 1) {
      pr += __shfl_down(pr, off); pz += __shfl_down(pz, off); pn += __shfl_down(pn, off);
    }
    if (kc == 0) {
      const float rg = fast_sigmoid(gr0 + gbr + pr);
      const float zg = fast_sigmoid(gz0 + gbz + pz);
      const float nn = fast_tanh(gn0 + rg * (pn + gbn));
      const float hn = (1.f - zg) * nn + zg * hprev;
      hprev = hn;
      *(volatile float*)(hall + (size_t)t * H + jg) = hn;
    }
  }
}

// router scan: 8 WGs x 512 (off critical path, R5-proven verbatim)
__device__ void router_scan(const float* __restrict__ GI, const float* __restrict__ whh,
                            const float* __restrict__ bhh, float* __restrict__ hs,
                            float* __restrict__ sm, int wg)
{
  float* hsmB = sm;              // 16 rows x 260 (k-major per batch row, pad 4)
  float* pbuf = sm + 16 * 260;   // 16*32*3 partials
  const int tid = threadIdx.x;
  const int j = tid >> 4, kc = tid & 15;
  const int jg = wg * 32 + j;
  float4 wr4[4], wz4[4], wn4[4];
#pragma unroll
  for (int i4 = 0; i4 < 4; ++i4) {
    const int kk = kc * 16 + ((i4 + kc) & 3) * 4;
    wr4[i4] = *(const float4*)(whh + (size_t)jg * 256 + kk);
    wz4[i4] = *(const float4*)(whh + (size_t)(256 + jg) * 256 + kk);
    wn4[i4] = *(const float4*)(whh + (size_t)(512 + jg) * 256 + kk);
  }
  const int b2 = tid >> 5, j2 = tid & 31;       // gate-stage identity
  const int jg2 = wg * 32 + j2;
  const float gbr = bhh[jg2], gbz = bhh[256 + jg2], gbn = bhh[512 + jg2];
  float gr0, gz0, gn0, gr1, gz1, gn1;
  { const float* g = GI + (size_t)b2 * RTOT;        gr0 = g[jg2]; gz0 = g[256 + jg2]; gn0 = g[512 + jg2]; }
  { const float* g = GI + (size_t)(16 + b2) * RTOT; gr1 = g[jg2]; gz1 = g[256 + jg2]; gn1 = g[512 + jg2]; }
  const int pb = tid >> 5, pk = (tid & 31) * 8;  // poll/stage identity: 8 elems/thread

  for (int t = 0; t < TT; ++t) {
    float gr2 = 0.f, gz2 = 0.f, gn2 = 0.f;
    if (t + 2 < TT) {
      const float* g = GI + (size_t)((t + 2) * 16 + b2) * RTOT;
      gr2 = g[jg2]; gz2 = g[256 + jg2]; gn2 = g[512 + jg2];
    }
    float v[8];
    if (t == 0) {
#pragma unroll
      for (int u = 0; u < 8; ++u) v[u] = 0.f;
    } else {
      const volatile float* q = (const volatile float*)(hs + (size_t)(t - 1) * 4096 + tid * 8);
#pragma unroll
      for (int u = 0; u < 8; ++u) v[u] = q[u];
      bool bad = true;
      while (bad) {
        bad = false;
#pragma unroll
        for (int u = 0; u < 8; ++u)
          if (is_poison(v[u])) { v[u] = q[u]; bad = true; }
      }
    }
    __syncthreads();               // prev readers done with hsmB
    *(float4*)(hsmB + pb * 260 + pk)     = make_float4(v[0], v[1], v[2], v[3]);
    *(float4*)(hsmB + pb * 260 + pk + 4) = make_float4(v[4], v[5], v[6], v[7]);
    __syncthreads();
    float ar[16], az[16], an[16];
#pragma unroll
    for (int b = 0; b < 16; ++b) { ar[b] = 0.f; az[b] = 0.f; an[b] = 0.f; }
#pragma unroll
    for (int i4 = 0; i4 < 4; ++i4) {
      const int col = kc * 16 + ((i4 + kc) & 3) * 4;
#pragma unroll
      for (int b = 0; b < 16; ++b) {
        const float4 h4 = *(const float4*)(hsmB + b * 260 + col);
        ar[b] = fmaf(wr4[i4].x, h4.x, ar[b]); ar[b] = fmaf(wr4[i4].y, h4.y, ar[b]);
        ar[b] = fmaf(wr4[i4].z, h4.z, ar[b]); ar[b] = fmaf(wr4[i4].w, h4.w, ar[b]);
        az[b] = fmaf(wz4[i4].x, h4.x, az[b]); az[b] = fmaf(wz4[i4].y, h4.y, az[b]);
        az[b] = fmaf(wz4[i4].z, h4.z, az[b]); az[b] = fmaf(wz4[i4].w, h4.w, az[b]);
        an[b] = fmaf(wn4[i4].x, h4.x, an[b]); an[b] = fmaf(wn4[i4].y, h4.y, an[b]);
        an[b] = fmaf(wn4[i4].z, h4.z, an[b]); an[b] = fmaf(wn4[i4].w, h4.w, an[b]);
      }
    }
#pragma unroll
    for (int off = 8; off; off >>= 1) {
#pragma unroll
      for (int b = 0; b < 16; ++b) {
        ar[b] += __shfl_down(ar[b], off);
        az[b] += __shfl_down(az[b], off);
        an[b] += __shfl_down(an[b], off);
      }
    }
    if (kc == 0) {
#pragma unroll
      for (int b = 0; b < 16; ++b) {
        pbuf[(b * 32 + j) * 3 + 0] = ar[b];
        pbuf[(b * 32 + j) * 3 + 1] = az[b];
        pbuf[(b * 32 + j) * 3 + 2] = an[b];
      }
    }
    __syncthreads();
    const float pr = pbuf[(b2 * 32 + j2) * 3 + 0];
    const float pz = pbuf[(b2 * 32 + j2) * 3 + 1];
    const float pn = pbuf[(b2 * 32 + j2) * 3 + 2];
    const float hprev = hsmB[b2 * 260 + jg2];
    const float rg = 1.f / (1.f + expf(-(gr0 + gbr + pr)));
    const float zg = 1.f / (1.f + expf(-(gz0 + gbz + pz)));
    const float nn = tanhf(gn0 + rg * (pn + gbn));
    const float hn = (1.f - zg) * nn + zg * hprev;
    *(volatile float*)(hs + (size_t)t * 4096 + b2 * 256 + jg2) = hn;
    gr0 = gr1; gz0 = gz1; gn0 = gn1;
    gr1 = gr2; gz1 = gz2; gn1 = gn2;
  }
}

__global__ __launch_bounds__(512, 1) void scan_kernel(ScanArgs A)
{
  __shared__ __attribute__((aligned(16))) float sm[16 * 260 + 1536];
  __shared__ int role_s[2];
  if (threadIdx.x == 0) {
    unsigned x;
    asm volatile("s_getreg_b32 %0, hwreg(HW_REG_XCC_ID)" : "=s"(x));
    const int xcd = (int)(x & 7u);
    role_s[0] = xcd;
    role_s[1] = atomicAdd(A.cnt + xcd, 1);  // device-scope, claim rank within my XCD
  }
  __syncthreads();
  const int xcd = role_s[0], r = role_s[1];
  if (xcd == 0)      { if (r < 32) expert_scan4w<512, 16>(A.GI + E3OFF, A.w3, A.b3, A.ha3, sm, r); }
  else if (xcd == 1) { if (r < 8)  router_scan(A.GI, A.rwhh, A.rbhh, A.hs, sm, r); }
  else if (xcd == 2) { if (r < 16) expert_scan4w<256, 16>(A.GI + E2OFF, A.w2, A.b2, A.ha2, sm, r); }
  else if (xcd == 3) { if (r < 4)  expert_scan<128, 32>(A.GI + E1OFF, A.w1, A.b1, A.ha1, sm, r); }
  // all other WGs exit immediately (roles over-provisioned)
}

// ================= phase 3a: router head, softmax, eul/task atomics =================
__global__ __launch_bounds__(256) void router_out_kernel(
    const float* __restrict__ hs, const float* __restrict__ ow, const float* __restrict__ ob,
    const int* __restrict__ tids, float* __restrict__ raw_out,
    float* __restrict__ tsum, float* __restrict__ tcnt)
{
  const int tid = threadIdx.x;
  const int lane = tid & 63, w = tid >> 6;
  const int n = blockIdx.x * 4 + w;
  float s0 = 0.f, s1 = 0.f, s2 = 0.f, s3 = 0.f;
#pragma unroll
  for (int q = 0; q < 4; ++q) {
    const int jj = lane + q * 64;
    float h = hs[(size_t)n * 256 + jj];
    h = h > 0.f ? h : 0.f;
    s0 = fmaf(h, ow[jj], s0);
    s1 = fmaf(h, ow[256 + jj], s1);
    s2 = fmaf(h, ow[512 + jj], s2);
    s3 = fmaf(h, ow[768 + jj], s3);
  }
  for (int off = 32; off; off >>= 1) {
    s0 += __shfl_xor(s0, off); s1 += __shfl_xor(s1, off);
    s2 += __shfl_xor(s2, off); s3 += __shfl_xor(s3, off);
  }
  if (lane == 0) {
    const float l0 = s0 + ob[0], l1 = s1 + ob[1], l2 = s2 + ob[2], l3 = s3 + ob[3];
    const float m = fmaxf(fmaxf(l0, l1), fmaxf(l2, l3));
    const float e0 = expf(l0 - m), e1 = expf(l1 - m), e2 = expf(l2 - m), e3 = expf(l3 - m);
    const float inv = 1.f / (e0 + e1 + e2 + e3);
    float4 rv; rv.x = e0 * inv; rv.y = e1 * inv; rv.z = e2 * inv; rv.w = e3 * inv;
    *(float4*)(raw_out + (size_t)n * 4) = rv;
    const float eul = rv.y * 128.f + rv.z * 256.f + rv.w * 512.f;
    const int tk = tids[n];
    atomicAdd(&tsum[tk], eul);
    atomicAdd(&tcnt[tk], 1.f);
  }
}

// ================= phase 3b: BN stats per column =================
__global__ __launch_bounds__(256) void bn_stats_kernel(
    const float* __restrict__ h1, const float* __restrict__ h2, const float* __restrict__ h3,
    float* __restrict__ mu, float* __restrict__ rstd)
{
  const int c = blockIdx.x;
  const float* hp; int He, hc;
  if (c < 128)      { hp = h1; He = 128; hc = c; }
  else if (c < 384) { hp = h2; He = 256; hc = c - 128; }
  else              { hp = h3; He = 512; hc = c - 384; }
  float s = 0.f, s2 = 0.f;
  for (int r = threadIdx.x; r < NTOK; r += 256) {
    const float v = hp[(size_t)r * He + hc];
    s += v; s2 = fmaf(v, v, s2);
  }
  for (int off = 32; off; off >>= 1) { s += __shfl_xor(s, off); s2 += __shfl_xor(s2, off); }
  __shared__ float red[8];
  const int lane = threadIdx.x & 63, w = threadIdx.x >> 6;
  if (lane == 0) { red[w] = s; red[4 + w] = s2; }
  __syncthreads();
  if (threadIdx.x == 0) {
    const float S = red[0] + red[1] + red[2] + red[3];
    const float S2 = red[4] + red[5] + red[6] + red[7];
    const float m = S * (1.f / 4096.f);
    float v = S2 * (1.f / 4096.f) - m * m;
    v = v > 0.f ? v : 0.f;
    mu[c] = m;
    rstd[c] = 1.f / sqrtf(v + 1e-5f);
  }
}

// ================= phase 3c: A' = gate * relu(bn(h)); plus task losses =================
__global__ __launch_bounds__(256) void aprime_kernel(
    const float* __restrict__ h1, const float* __restrict__ h2, const float* __restrict__ h3,
    const float* __restrict__ g1, const float* __restrict__ be1,
    const float* __restrict__ g2, const float* __restrict__ be2,
    const float* __restrict__ g3, const float* __restrict__ be3,
    const float* __restrict__ mu, const float* __restrict__ rstd,
    const float* __restrict__ raw, float* __restrict__ Ap,
    const float* __restrict__ tsum, const float* __restrict__ tcnt, float* __restrict__ tl_out)
{
  if (blockIdx.x == 4096) {
    if (threadIdx.x < 4) tl_out[threadIdx.x] = tsum[threadIdx.x] / tcnt[threadIdx.x];
    return;
  }
  const int n = blockIdx.x;
  for (int c = threadIdx.x; c < 896; c += 256) {
    const float* hp; const float* gg; const float* bb; int He, hc, e;
    if (c < 128)      { hp = h1; gg = g1; bb = be1; He = 128; hc = c;       e = 1; }
    else if (c < 384) { hp = h2; gg = g2; bb = be2; He = 256; hc = c - 128; e = 2; }
    else              { hp = h3; gg = g3; bb = be3; He = 512; hc = c - 384; e = 3; }
    const float h = hp[(size_t)n * He + hc];
    float v = (h - mu[c]) * rstd[c] * gg[hc] + bb[hc];
    v = v > 0.f ? v : 0.f;
    Ap[(size_t)n * 896 + c] = raw[(size_t)n * 4 + e] * v;
  }
}

// ================= phase 4: out = A' @ OWc^T + gated biases + g0*x =================
__global__ __launch_bounds__(256) void out_gemm_kernel(
    const float* __restrict__ Ap,
    const float* __restrict__ ow1, const float* __restrict__ ow2, const float* __restrict__ ow3,
    const float* __restrict__ ob1, const float* __restrict__ ob2, const float* __restrict__ ob3,
    const float* __restrict__ X, const float* __restrict__ raw, float* __restrict__ out)
{
  __shared__ float At[32*64];
  __shared__ float Bt[32*64];
  const int n0 = blockIdx.x * 64;
  const int d0 = blockIdx.y * 64;
  const int tid = threadIdx.x;
  const int lm = tid & 63, lk4 = tid >> 6;
  const int tx = tid & 15, ty = tid >> 4;
  float acc[4][4];
#pragma unroll
  for (int i = 0; i < 4; ++i)
#pragma unroll
    for (int q = 0; q < 4; ++q) acc[i][q] = 0.f;

  for (int kb = 0; kb < 896; kb += 32) {
    const float* W; int He, ko;
    if (kb < 128)      { W = ow1; He = 128; ko = 0; }
    else if (kb < 384) { W = ow2; He = 256; ko = 128; }
    else               { W = ow3; He = 512; ko = 384; }
    const float4 a0 = *(const float4*)(Ap + (size_t)(n0+lm)*896 + kb + lk4*8);
    const float4 a1 = *(const float4*)(Ap + (size_t)(n0+lm)*896 + kb + lk4*8 + 4);
    const float4 c0 = *(const float4*)(W + (size_t)(d0+lm)*He + (kb - ko) + lk4*8);
    const float4 c1 = *(const float4*)(W + (size_t)(d0+lm)*He + (kb - ko) + lk4*8 + 4);
    __syncthreads();
    At[(lk4*8+0)*64+lm]=a0.x; At[(lk4*8+1)*64+lm]=a0.y; At[(lk4*8+2)*64+lm]=a0.z; At[(lk4*8+3)*64+lm]=a0.w;
    At[(lk4*8+4)*64+lm]=a1.x; At[(lk4*8+5)*64+lm]=a1.y; At[(lk4*8+6)*64+lm]=a1.z; At[(lk4*8+7)*64+lm]=a1.w;
    Bt[(lk4*8+0)*64+lm]=c0.x; Bt[(lk4*8+1)*64+lm]=c0.y; Bt[(lk4*8+2)*64+lm]=c0.z; Bt[(lk4*8+3)*64+lm]=c0.w;
    Bt[(lk4*8+4)*64+lm]=c1.x; Bt[(lk4*8+5)*64+lm]=c1.y; Bt[(lk4*8+6)*64+lm]=c1.z; Bt[(lk4*8+7)*64+lm]=c1.w;
    __syncthreads();
#pragma unroll
    for (int k = 0; k < 32; ++k) {
      const float4 av = *(const float4*)&At[k*64 + ty*4];
      const float4 bv = *(const float4*)&Bt[k*64 + tx*4];
      acc[0][0]=fmaf(av.x,bv.x,acc[0][0]); acc[0][1]=fmaf(av.x,bv.y,acc[0][1]); acc[0][2]=fmaf(av.x,bv.z,acc[0][2]); acc[0][3]=fmaf(av.x,bv.w,acc[0][3]);
      acc[1][0]=fmaf(av.y,bv.x,acc[1][0]); acc[1][1]=fmaf(av.y,bv.y,acc[1][1]); acc[1][2]=fmaf(av.y,bv.z,acc[1][2]); acc[1][3]=fmaf(av.y,bv.w,acc[1][3]);
      acc[2][0]=fmaf(av.z,bv.x,acc[2][0]); acc[2][1]=fmaf(av.z,bv.y,acc[2][1]); acc[2][2]=fmaf(av.z,bv.z,acc[2][2]); acc[2][3]=fmaf(av.z,bv.w,acc[2][3]);
      acc[3][0]=fmaf(av.w,bv.x,acc[3][0]); acc[3][1]=fmaf(av.w,bv.y,acc[3][1]); acc[3][2]=fmaf(av.w,bv.z,acc[3][2]); acc[3][3]=fmaf(av.w,bv.w,acc[3][3]);
    }
  }
#pragma unroll
  for (int i = 0; i < 4; ++i) {
    const int n = n0 + ty * 4 + i;
    const float4 g  = *(const float4*)(raw + (size_t)n * 4);
    const float4 xv = *(const float4*)(X + (size_t)n * 512 + d0 + tx * 4);
    const float4 o1 = *(const float4*)(ob1 + d0 + tx * 4);
    const float4 o2 = *(const float4*)(ob2 + d0 + tx * 4);
    const float4 o3 = *(const float4*)(ob3 + d0 + tx * 4);
    float4 o;
    o.x = acc[i][0] + g.x*xv.x + g.y*o1.x + g.z*o2.x + g.w*o3.x;
    o.y = acc[i][1] + g.x*xv.y + g.y*o1.y + g.z*o2.y + g.w*o3.y;
    o.z = acc[i][2] + g.x*xv.z + g.y*o1.z + g.z*o2.z + g.w*o3.z;
    o.w = acc[i][3] + g.x*xv.w + g.y*o1.w + g.z*o2.w + g.w*o3.w;
    *(float4*)(out + (size_t)n * 512 + d0 + tx * 4) = o;
  }
}

// ================= host =================
extern "C" void kernel_launch(void* const* d_in, const int* in_sizes, int n_in,
                              void* d_out, int out_size, void* d_ws, size_t ws_size,
                              hipStream_t stream) {
  const float* x    = (const float*)d_in[0];
  const int*   tids = (const int*)d_in[1];
  const float* rwih = (const float*)d_in[2];
  const float* rwhh = (const float*)d_in[3];
  const float* rbih = (const float*)d_in[4];
  const float* rbhh = (const float*)d_in[5];
  const float* row  = (const float*)d_in[6];
  const float* rob  = (const float*)d_in[7];
  const float* w1ih = (const float*)d_in[8];
  const float* w1hh = (const float*)d_in[9];
  const float* b1ih = (const float*)d_in[10];
  const float* b1hh = (const float*)d_in[11];
  const float* bn1g = (const float*)d_in[12];
  const float* bn1b = (const float*)d_in[13];
  const float* ow1  = (const float*)d_in[14];
  const float* ob1  = (const float*)d_in[15];
  const float* w2ih = (const float*)d_in[16];
  const float* w2hh = (const float*)d_in[17];
  const float* b2ih = (const float*)d_in[18];
  const float* b2hh = (const float*)d_in[19];
  const float* bn2g = (const float*)d_in[20];
  const float* bn2b = (const float*)d_in[21];
  const float* ow2  = (const float*)d_in[22];
  const float* ob2  = (const float*)d_in[23];
  const float* w3ih = (const float*)d_in[24];
  const float* w3hh = (const float*)d_in[25];
  const float* b3ih = (const float*)d_in[26];
  const float* b3hh = (const float*)d_in[27];
  const float* bn3g = (const float*)d_in[28];
  const float* bn3b = (const float*)d_in[29];
  const float* ow3  = (const float*)d_in[30];
  const float* ob3  = (const float*)d_in[31];

  char* ws = (char*)d_ws;
  float* tsum = (float*)(ws + OFF_TSUM);
  float* tcnt = (float*)(ws + OFF_TCNT);
  int*   cnt  = (int*)(ws + OFF_CNT);
  float* GI   = (float*)(ws + OFF_GI);
  float* hs   = (float*)(ws + OFF_HS);
  float* ha3  = (float*)(ws + OFF_HA3);
  float* ha2  = (float*)(ws + OFF_HA2);
  float* ha1  = (float*)(ws + OFF_HA1);
  float* Ap   = (float*)(ws + OFF_AP);
  float* mu   = (float*)(ws + OFF_MU);
  float* rstd = (float*)(ws + OFF_RSTD);

  float* outp = (float*)d_out;
  float* rawp = outp + (size_t)NTOK * DD;
  float* tlp  = rawp + (size_t)NTOK * 4;

  // zero claim counters + task accumulators; self-poison the h-history exchange
  // buffers (value==0xAAAAAAAA is the "not ready" sentinel the scan polls against)
  hipMemsetAsync(ws, 0, ZBYTES, stream);
  hipMemsetAsync(ws + OFF_HS, 0xAA, POISON_BYTES, stream);

  // phase 1: input projections for router + all experts
  gemm1_kernel<<<dim3(64, 54), 256, 0, stream>>>(x, rwih, w1ih, w2ih, w3ih,
                                                 rbih, b1ih, b2ih, b3ih, GI);

  // phase 2: XCD-claimed persistent scans (60 role WGs; intra-XCD L2 exchange)
  ScanArgs sa;
  sa.GI = GI; sa.rwhh = rwhh; sa.rbhh = rbhh; sa.hs = hs;
  sa.w1 = w1hh; sa.b1 = b1hh; sa.ha1 = ha1;
  sa.w2 = w2hh; sa.b2 = b2hh; sa.ha2 = ha2;
  sa.w3 = w3hh; sa.b3 = b3hh; sa.ha3 = ha3;
  sa.cnt = cnt;
  scan_kernel<<<dim3(320), dim3(512), 0, stream>>>(sa);

  // phase 3: router head + task-loss atomics; BN stats; A' build (+ task losses)
  router_out_kernel<<<dim3(1024), 256, 0, stream>>>(hs, row, rob, tids, rawp, tsum, tcnt);
  bn_stats_kernel<<<dim3(896), 256, 0, stream>>>(ha1, ha2, ha3, mu, rstd);
  aprime_kernel<<<dim3(4097), 256, 0, stream>>>(ha1, ha2, ha3, bn1g, bn1b, bn2g, bn2b,
                                                bn3g, bn3b, mu, rstd, rawp, Ap,
                                                tsum, tcnt, tlp);

  // phase 4: gated expert-output GEMM + identity expert + gated biases
  out_gemm_kernel<<<dim3(64, 8), 256, 0, stream>>>(Ap, ow1, ow2, ow3, ob1, ob2, ob3,
                                                   x, rawp, outp);
}

// Round 8
// 6405.731 us; speedup vs baseline: 1.7228x; 1.0404x over previous
//
#include <hip/hip_runtime.h>
#include <math.h>

// ---------------- problem constants ----------------
constexpr int TT = 256, BB = 16, DD = 512;
constexpr int NTOK = 4096;                 // T*B
constexpr int RTOT = 3456;                 // 768 + 384 + 768 + 1536
constexpr int E1OFF = 768, E2OFF = 1152, E3OFF = 1920;
constexpr int NROLES = 52;                 // 32 e3 + 8 router + 8 e2 + 4 e1

// ---------------- workspace layout (bytes) ----------------
constexpr size_t OFF_TSUM = 0;                                   // 4 f
constexpr size_t OFF_TCNT = 16;                                  // 4 f
constexpr size_t OFF_CNT  = 32;                                  // 8 ints (XCD claim counters)
constexpr size_t OFF_DONE = 64;                                  // 1 int (role completion)
constexpr size_t ZBYTES   = 128;
constexpr size_t OFF_GI   = 4096;
constexpr size_t OFF_HS   = OFF_GI  + (size_t)NTOK*RTOT*4;       // router h history (poll target)
constexpr size_t OFF_HA3  = OFF_HS  + (size_t)NTOK*256*4;
constexpr size_t OFF_HA2  = OFF_HA3 + (size_t)NTOK*512*4;
constexpr size_t OFF_HA1  = OFF_HA2 + (size_t)NTOK*256*4;
constexpr size_t OFF_AP   = OFF_HA1 + (size_t)NTOK*128*4;
constexpr size_t OFF_MU   = OFF_AP  + (size_t)NTOK*896*4;
constexpr size_t OFF_RSTD = OFF_MU  + 896*4;
constexpr size_t POISON_BYTES = (size_t)NTOK*(256+512+256+128)*4;  // HS..HA1 contiguous

__device__ __forceinline__ bool is_poison(float v) {
  return __float_as_uint(v) == 0xAAAAAAAAu;
}

// fast, clamped activations (~2ulp; validated in R5: absmax unchanged)
__device__ __forceinline__ float fast_sigmoid(float x) {
  const float xc = fminf(fmaxf(x, -30.f), 30.f);
  return __fdividef(1.f, 1.f + __expf(-xc));
}
__device__ __forceinline__ float fast_tanh(float x) {
  const float xc = fminf(fmaxf(x, -15.f), 15.f);
  const float e = __expf(-2.f * xc);
  return (1.f - e) * __fdividef(1.f, 1.f + e);
}

// ================= phase 1: gi = x @ Wih^T + b_ih (all 3456 rows) =================
__global__ __launch_bounds__(256) void gemm1_kernel(
    const float* __restrict__ X,
    const float* __restrict__ wR, const float* __restrict__ w1,
    const float* __restrict__ w2, const float* __restrict__ w3,
    const float* __restrict__ bR, const float* __restrict__ b1,
    const float* __restrict__ b2, const float* __restrict__ b3,
    float* __restrict__ GI)
{
  __shared__ float At[32*64];
  __shared__ float Bt[32*64];
  const int n0 = blockIdx.x * 64;
  const int r0 = blockIdx.y * 64;
  const float* W; const float* bias; int rs;
  if (r0 < 768)       { W = wR; bias = bR; rs = 0; }
  else if (r0 < 1152) { W = w1; bias = b1; rs = 768; }
  else if (r0 < 1920) { W = w2; bias = b2; rs = 1152; }
  else                { W = w3; bias = b3; rs = 1920; }
  const int lr0 = r0 - rs;
  const int tid = threadIdx.x;
  const int lm = tid & 63, lk4 = tid >> 6;
  const int tx = tid & 15, ty = tid >> 4;
  float acc[4][4];
#pragma unroll
  for (int i = 0; i < 4; ++i)
#pragma unroll
    for (int q = 0; q < 4; ++q) acc[i][q] = 0.f;

  for (int kb = 0; kb < 512; kb += 32) {
    const float4 a0 = *(const float4*)(X + (size_t)(n0+lm)*512 + kb + lk4*8);
    const float4 a1 = *(const float4*)(X + (size_t)(n0+lm)*512 + kb + lk4*8 + 4);
    const float4 c0 = *(const float4*)(W + (size_t)(lr0+lm)*512 + kb + lk4*8);
    const float4 c1 = *(const float4*)(W + (size_t)(lr0+lm)*512 + kb + lk4*8 + 4);
    __syncthreads();
    At[(lk4*8+0)*64+lm]=a0.x; At[(lk4*8+1)*64+lm]=a0.y; At[(lk4*8+2)*64+lm]=a0.z; At[(lk4*8+3)*64+lm]=a0.w;
    At[(lk4*8+4)*64+lm]=a1.x; At[(lk4*8+5)*64+lm]=a1.y; At[(lk4*8+6)*64+lm]=a1.z; At[(lk4*8+7)*64+lm]=a1.w;
    Bt[(lk4*8+0)*64+lm]=c0.x; Bt[(lk4*8+1)*64+lm]=c0.y; Bt[(lk4*8+2)*64+lm]=c0.z; Bt[(lk4*8+3)*64+lm]=c0.w;
    Bt[(lk4*8+4)*64+lm]=c1.x; Bt[(lk4*8+5)*64+lm]=c1.y; Bt[(lk4*8+6)*64+lm]=c1.z; Bt[(lk4*8+7)*64+lm]=c1.w;
    __syncthreads();
#pragma unroll
    for (int k = 0; k < 32; ++k) {
      const float4 av = *(const float4*)&At[k*64 + ty*4];
      const float4 bv = *(const float4*)&Bt[k*64 + tx*4];
      acc[0][0]=fmaf(av.x,bv.x,acc[0][0]); acc[0][1]=fmaf(av.x,bv.y,acc[0][1]); acc[0][2]=fmaf(av.x,bv.z,acc[0][2]); acc[0][3]=fmaf(av.x,bv.w,acc[0][3]);
      acc[1][0]=fmaf(av.y,bv.x,acc[1][0]); acc[1][1]=fmaf(av.y,bv.y,acc[1][1]); acc[1][2]=fmaf(av.y,bv.z,acc[1][2]); acc[1][3]=fmaf(av.y,bv.w,acc[1][3]);
      acc[2][0]=fmaf(av.z,bv.x,acc[2][0]); acc[2][1]=fmaf(av.z,bv.y,acc[2][1]); acc[2][2]=fmaf(av.z,bv.z,acc[2][2]); acc[2][3]=fmaf(av.z,bv.w,acc[2][3]);
      acc[3][0]=fmaf(av.w,bv.x,acc[3][0]); acc[3][1]=fmaf(av.w,bv.y,acc[3][1]); acc[3][2]=fmaf(av.w,bv.z,acc[3][2]); acc[3][3]=fmaf(av.w,bv.w,acc[3][3]);
    }
  }
  const float4 bb = *(const float4*)(bias + lr0 + tx*4);
#pragma unroll
  for (int i = 0; i < 4; ++i) {
    float4 o;
    o.x = acc[i][0] + bb.x; o.y = acc[i][1] + bb.y; o.z = acc[i][2] + bb.z; o.w = acc[i][3] + bb.w;
    *(float4*)(GI + (size_t)(n0+ty*4+i)*RTOT + r0 + tx*4) = o;
  }
}

// ================= phase 2: persistent scans (XCD-claimed roles) =================
// DVFS test round: step time (1030ns LDS-only .. 1500ns cross-WG) has been
// invariant to exchange/barrier/LDS-op/wave-count/register changes across 7
// rounds; serial-chain arithmetic at spec latencies predicts ~250-400ns.
// Hypothesis: utilization-governed downclock (scan = 60 WGs, 4-6% VALUBusy).
// Test: over-provisioned WGs become low-priority FMA HEATER waves keeping all
// 256 CUs busy until the 52 role WGs signal completion. Role waves take
// s_setprio(1) so heaters lose issue arbitration on shared CUs.
struct ScanArgs {
  const float* GI;
  const float* rwhh; const float* rbhh; float* hs;
  const float* w1; const float* b1; float* ha1;
  const float* w2; const float* b2; float* ha2;
  const float* w3; const float* b3; float* ha3;
  int* cnt; int* done;
};

// expert scan over 4096 flat tokens. 512 threads/WG. OPW outputs per WG.
// (R5-proven verbatim: poll -> stage -> barrier -> lane-held gi -> compute)
template<int H, int OPW>
__device__ void expert_scan(const float* __restrict__ GIe, const float* __restrict__ whh,
                            const float* __restrict__ bhh, float* __restrict__ hall,
                            float* __restrict__ sm, int wg)
{
  constexpr int KCN = 512 / OPW;
  constexpr int CHUNK = H / KCN;
  constexpr int NF4 = CHUNK / 4;
  const int tid = threadIdx.x;
  const int j = tid / KCN, kc = tid % KCN;
  const int jg = wg * OPW + j;
  const int lane = tid & 63;

  float4 wr[NF4], wz[NF4], wn[NF4];     // <=12 float4 -> register-resident
#pragma unroll
  for (int i4 = 0; i4 < NF4; ++i4) {
    const int kk = kc * CHUNK + ((i4 + kc) & (NF4 - 1)) * 4;   // bank-rotated
    wr[i4] = *(const float4*)(whh + (size_t)jg * H + kk);
    wz[i4] = *(const float4*)(whh + (size_t)(H + jg) * H + kk);
    wn[i4] = *(const float4*)(whh + (size_t)(2*H + jg) * H + kk);
  }
  float gbr = 0.f, gbz = 0.f, gbn = 0.f, hprev = 0.f;
  if (kc == 0) { gbr = bhh[jg]; gbz = bhh[H + jg]; gbn = bhh[2*H + jg]; }

  // gi lane-held double buffer: lane kc holds gi(t) for t == block*KCN + kc
  float gAr, gAz, gAn, gBr, gBz, gBn;
  { const float* g = GIe + (size_t)kc * RTOT;
    gAr = g[jg]; gAz = g[H + jg]; gAn = g[2*H + jg]; }
  { const float* g = GIe + (size_t)(KCN + kc) * RTOT;
    gBr = g[jg]; gBz = g[H + jg]; gBn = g[2*H + jg]; }

  for (int t = 0; t < NTOK; ++t) {
    // ---- poll h(t-1): mass-parallel scalar poison-poll ----
    float val = 0.f;
    if (tid < H && t > 0) {
      const volatile float* p = (const volatile float*)(hall + (size_t)(t - 1) * H + tid);
      val = *p;
      while (is_poison(val)) val = *p;
    }
    if (tid < H) sm[(size_t)(t & 1) * H + tid] = val;
    __syncthreads();                      // single barrier per step (parity-safe)
    const float* hbuf = sm + (size_t)(t & 1) * H;

    const int m = t & (KCN - 1);
    const int src = (lane & ~(KCN - 1)) | m;
    const float gr0 = __shfl(gAr, src);
    const float gz0 = __shfl(gAz, src);
    const float gn0 = __shfl(gAn, src);

    float pr = 0.f, pz = 0.f, pn = 0.f;
#pragma unroll
    for (int i4 = 0; i4 < NF4; ++i4) {
      const float4 h4 = *(const float4*)(hbuf + kc * CHUNK + ((i4 + kc) & (NF4 - 1)) * 4);
      pr = fmaf(wr[i4].x, h4.x, pr); pr = fmaf(wr[i4].y, h4.y, pr);
      pr = fmaf(wr[i4].z, h4.z, pr); pr = fmaf(wr[i4].w, h4.w, pr);
      pz = fmaf(wz[i4].x, h4.x, pz); pz = fmaf(wz[i4].y, h4.y, pz);
      pz = fmaf(wz[i4].z, h4.z, pz); pz = fmaf(wz[i4].w, h4.w, pz);
      pn = fmaf(wn[i4].x, h4.x, pn); pn = fmaf(wn[i4].y, h4.y, pn);
      pn = fmaf(wn[i4].w, h4.w, pn); pn = fmaf(wn[i4].z, h4.z, pn);
    }
#pragma unroll
    for (int off = KCN / 2; off; off >>= 1) {
      pr += __shfl_down(pr, off); pz += __shfl_down(pz, off); pn += __shfl_down(pn, off);
    }
    if (kc == 0) {
      const float rg = fast_sigmoid(gr0 + gbr + pr);
      const float zg = fast_sigmoid(gz0 + gbz + pz);
      const float nn = fast_tanh(gn0 + rg * (pn + gbn));
      const float hn = (1.f - zg) * nn + zg * hprev;
      hprev = hn;
      *(volatile float*)(hall + (size_t)t * H + jg) = hn;   // message + history
    }
    // block rollover at end of step (R5-proven placement)
    if (m == KCN - 1) {
      gAr = gBr; gAz = gBz; gAn = gBn;
      const int nb = t + 1 + KCN;
      if (nb + kc < NTOK) {
        const float* g = GIe + (size_t)(nb + kc) * RTOT;
        gBr = g[jg]; gBz = g[H + jg]; gBn = g[2*H + jg];
      }
    }
  }
}

// router scan: 8 WGs x 512 (R5-proven verbatim; off critical path)
__device__ void router_scan(const float* __restrict__ GI, const float* __restrict__ whh,
                            const float* __restrict__ bhh, float* __restrict__ hs,
                            float* __restrict__ sm, int wg)
{
  float* hsmB = sm;              // 16 rows x 260 (k-major per batch row, pad 4)
  float* pbuf = sm + 16 * 260;   // 16*32*3 partials
  const int tid = threadIdx.x;
  const int j = tid >> 4, kc = tid & 15;
  const int jg = wg * 32 + j;
  float4 wr4[4], wz4[4], wn4[4];
#pragma unroll
  for (int i4 = 0; i4 < 4; ++i4) {
    const int kk = kc * 16 + ((i4 + kc) & 3) * 4;
    wr4[i4] = *(const float4*)(whh + (size_t)jg * 256 + kk);
    wz4[i4] = *(const float4*)(whh + (size_t)(256 + jg) * 256 + kk);
    wn4[i4] = *(const float4*)(whh + (size_t)(512 + jg) * 256 + kk);
  }
  const int b2 = tid >> 5, j2 = tid & 31;       // gate-stage identity
  const int jg2 = wg * 32 + j2;
  const float gbr = bhh[jg2], gbz = bhh[256 + jg2], gbn = bhh[512 + jg2];
  float gr0, gz0, gn0, gr1, gz1, gn1;
  { const float* g = GI + (size_t)b2 * RTOT;        gr0 = g[jg2]; gz0 = g[256 + jg2]; gn0 = g[512 + jg2]; }
  { const float* g = GI + (size_t)(16 + b2) * RTOT; gr1 = g[jg2]; gz1 = g[256 + jg2]; gn1 = g[512 + jg2]; }
  const int pb = tid >> 5, pk = (tid & 31) * 8;  // poll/stage identity: 8 elems/thread

  for (int t = 0; t < TT; ++t) {
    float gr2 = 0.f, gz2 = 0.f, gn2 = 0.f;
    if (t + 2 < TT) {
      const float* g = GI + (size_t)((t + 2) * 16 + b2) * RTOT;
      gr2 = g[jg2]; gz2 = g[256 + jg2]; gn2 = g[512 + jg2];
    }
    float v[8];
    if (t == 0) {
#pragma unroll
      for (int u = 0; u < 8; ++u) v[u] = 0.f;
    } else {
      const volatile float* q = (const volatile float*)(hs + (size_t)(t - 1) * 4096 + tid * 8);
#pragma unroll
      for (int u = 0; u < 8; ++u) v[u] = q[u];
      bool bad = true;
      while (bad) {
        bad = false;
#pragma unroll
        for (int u = 0; u < 8; ++u)
          if (is_poison(v[u])) { v[u] = q[u]; bad = true; }
      }
    }
    __syncthreads();               // prev readers done with hsmB
    *(float4*)(hsmB + pb * 260 + pk)     = make_float4(v[0], v[1], v[2], v[3]);
    *(float4*)(hsmB + pb * 260 + pk + 4) = make_float4(v[4], v[5], v[6], v[7]);
    __syncthreads();
    float ar[16], az[16], an[16];
#pragma unroll
    for (int b = 0; b < 16; ++b) { ar[b] = 0.f; az[b] = 0.f; an[b] = 0.f; }
#pragma unroll
    for (int i4 = 0; i4 < 4; ++i4) {
      const int col = kc * 16 + ((i4 + kc) & 3) * 4;
#pragma unroll
      for (int b = 0; b < 16; ++b) {
        const float4 h4 = *(const float4*)(hsmB + b * 260 + col);
        ar[b] = fmaf(wr4[i4].x, h4.x, ar[b]); ar[b] = fmaf(wr4[i4].y, h4.y, ar[b]);
        ar[b] = fmaf(wr4[i4].z, h4.z, ar[b]); ar[b] = fmaf(wr4[i4].w, h4.w, ar[b]);
        az[b] = fmaf(wz4[i4].x, h4.x, az[b]); az[b] = fmaf(wz4[i4].y, h4.y, az[b]);
        az[b] = fmaf(wz4[i4].z, h4.z, az[b]); az[b] = fmaf(wz4[i4].w, h4.w, az[b]);
        an[b] = fmaf(wn4[i4].x, h4.x, an[b]); an[b] = fmaf(wn4[i4].y, h4.y, an[b]);
        an[b] = fmaf(wn4[i4].z, h4.z, an[b]); an[b] = fmaf(wn4[i4].w, h4.w, an[b]);
      }
    }
#pragma unroll
    for (int off = 8; off; off >>= 1) {
#pragma unroll
      for (int b = 0; b < 16; ++b) {
        ar[b] += __shfl_down(ar[b], off);
        az[b] += __shfl_down(az[b], off);
        an[b] += __shfl_down(an[b], off);
      }
    }
    if (kc == 0) {
#pragma unroll
      for (int b = 0; b < 16; ++b) {
        pbuf[(b * 32 + j) * 3 + 0] = ar[b];
        pbuf[(b * 32 + j) * 3 + 1] = az[b];
        pbuf[(b * 32 + j) * 3 + 2] = an[b];
      }
    }
    __syncthreads();
    const float pr = pbuf[(b2 * 32 + j2) * 3 + 0];
    const float pz = pbuf[(b2 * 32 + j2) * 3 + 1];
    const float pn = pbuf[(b2 * 32 + j2) * 3 + 2];
    const float hprev = hsmB[b2 * 260 + jg2];
    const float rg = 1.f / (1.f + expf(-(gr0 + gbr + pr)));
    const float zg = 1.f / (1.f + expf(-(gz0 + gbz + pz)));
    const float nn = tanhf(gn0 + rg * (pn + gbn));
    const float hn = (1.f - zg) * nn + zg * hprev;
    *(volatile float*)(hs + (size_t)t * 4096 + b2 * 256 + jg2) = hn;
    gr0 = gr1; gz0 = gz1; gn0 = gn1;
    gr1 = gr2; gz1 = gz2; gn1 = gn2;
  }
}

// heater: keep the CU's VALU busy (priority 0) until all roles signal done.
__device__ void heater(volatile int* done, float* sm)
{
  volatile int* stop = (volatile int*)sm;
  if (threadIdx.x == 0) *stop = 0;
  __syncthreads();
  float a0 = 1.f + threadIdx.x, a1 = 2.f, a2 = 3.f, a3 = 4.f;
  const float b = 1.0000001f, c = -0.0000001f;
  for (;;) {
    for (int i = 0; i < 256; ++i) {
      a0 = fmaf(a0, b, c); a1 = fmaf(a1, b, c);
      a2 = fmaf(a2, b, c); a3 = fmaf(a3, b, c);
    }
    asm volatile("" :: "v"(a0), "v"(a1), "v"(a2), "v"(a3));
    if (threadIdx.x == 0 &&
        __hip_atomic_load((const int*)done, __ATOMIC_RELAXED, __HIP_MEMORY_SCOPE_AGENT) >= NROLES)
      *stop = 1;
    __syncthreads();
    if (*stop) break;
    __syncthreads();
  }
}

__global__ __launch_bounds__(512, 1) void scan_kernel(ScanArgs A)
{
  __shared__ __attribute__((aligned(16))) float sm[16 * 260 + 1536];
  __shared__ int role_s[2];
  if (threadIdx.x == 0) {
    unsigned x;
    asm volatile("s_getreg_b32 %0, hwreg(HW_REG_XCC_ID)" : "=s"(x));
    const int xcd = (int)(x & 7u);
    role_s[0] = xcd;
    role_s[1] = atomicAdd(A.cnt + xcd, 1);  // device-scope, claim rank within my XCD
  }
  __syncthreads();
  const int xcd = role_s[0], r = role_s[1];
  bool had_role = true;
  if (xcd == 0 && r < 32) {
    __builtin_amdgcn_s_setprio(1);
    expert_scan<512, 16>(A.GI + E3OFF, A.w3, A.b3, A.ha3, sm, r);
  } else if (xcd == 1 && r < 8) {
    __builtin_amdgcn_s_setprio(1);
    router_scan(A.GI, A.rwhh, A.rbhh, A.hs, sm, r);
  } else if (xcd == 2 && r < 8) {
    __builtin_amdgcn_s_setprio(1);
    expert_scan<256, 32>(A.GI + E2OFF, A.w2, A.b2, A.ha2, sm, r);
  } else if (xcd == 3 && r < 4) {
    __builtin_amdgcn_s_setprio(1);
    expert_scan<128, 32>(A.GI + E1OFF, A.w1, A.b1, A.ha1, sm, r);
  } else {
    had_role = false;
  }
  if (had_role) {
    __builtin_amdgcn_s_setprio(0);
    __syncthreads();
    if (threadIdx.x == 0)
      __hip_atomic_fetch_add(A.done, 1, __ATOMIC_RELAXED, __HIP_MEMORY_SCOPE_AGENT);
  } else {
    heater(A.done, sm);   // DVFS test: keep all CUs hot until roles finish
  }
}

// ================= phase 3a: router head, softmax, eul/task atomics =================
__global__ __launch_bounds__(256) void router_out_kernel(
    const float* __restrict__ hs, const float* __restrict__ ow, const float* __restrict__ ob,
    const int* __restrict__ tids, float* __restrict__ raw_out,
    float* __restrict__ tsum, float* __restrict__ tcnt)
{
  const int tid = threadIdx.x;
  const int lane = tid & 63, w = tid >> 6;
  const int n = blockIdx.x * 4 + w;
  float s0 = 0.f, s1 = 0.f, s2 = 0.f, s3 = 0.f;
#pragma unroll
  for (int q = 0; q < 4; ++q) {
    const int jj = lane + q * 64;
    float h = hs[(size_t)n * 256 + jj];
    h = h > 0.f ? h : 0.f;
    s0 = fmaf(h, ow[jj], s0);
    s1 = fmaf(h, ow[256 + jj], s1);
    s2 = fmaf(h, ow[512 + jj], s2);
    s3 = fmaf(h, ow[768 + jj], s3);
  }
  for (int off = 32; off; off >>= 1) {
    s0 += __shfl_xor(s0, off); s1 += __shfl_xor(s1, off);
    s2 += __shfl_xor(s2, off); s3 += __shfl_xor(s3, off);
  }
  if (lane == 0) {
    const float l0 = s0 + ob[0], l1 = s1 + ob[1], l2 = s2 + ob[2], l3 = s3 + ob[3];
    const float m = fmaxf(fmaxf(l0, l1), fmaxf(l2, l3));
    const float e0 = expf(l0 - m), e1 = expf(l1 - m), e2 = expf(l2 - m), e3 = expf(l3 - m);
    const float inv = 1.f / (e0 + e1 + e2 + e3);
    float4 rv; rv.x = e0 * inv; rv.y = e1 * inv; rv.z = e2 * inv; rv.w = e3 * inv;
    *(float4*)(raw_out + (size_t)n * 4) = rv;
    const float eul = rv.y * 128.f + rv.z * 256.f + rv.w * 512.f;
    const int tk = tids[n];
    atomicAdd(&tsum[tk], eul);
    atomicAdd(&tcnt[tk], 1.f);
  }
}

// ================= phase 3b: BN stats per column =================
__global__ __launch_bounds__(256) void bn_stats_kernel(
    const float* __restrict__ h1, const float* __restrict__ h2, const float* __restrict__ h3,
    float* __restrict__ mu, float* __restrict__ rstd)
{
  const int c = blockIdx.x;
  const float* hp; int He, hc;
  if (c < 128)      { hp = h1; He = 128; hc = c; }
  else if (c < 384) { hp = h2; He = 256; hc = c - 128; }
  else              { hp = h3; He = 512; hc = c - 384; }
  float s = 0.f, s2 = 0.f;
  for (int r = threadIdx.x; r < NTOK; r += 256) {
    const float v = hp[(size_t)r * He + hc];
    s += v; s2 = fmaf(v, v, s2);
  }
  for (int off = 32; off; off >>= 1) { s += __shfl_xor(s, off); s2 += __shfl_xor(s2, off); }
  __shared__ float red[8];
  const int lane = threadIdx.x & 63, w = threadIdx.x >> 6;
  if (lane == 0) { red[w] = s; red[4 + w] = s2; }
  __syncthreads();
  if (threadIdx.x == 0) {
    const float S = red[0] + red[1] + red[2] + red[3];
    const float S2 = red[4] + red[5] + red[6] + red[7];
    const float m = S * (1.f / 4096.f);
    float v = S2 * (1.f / 4096.f) - m * m;
    v = v > 0.f ? v : 0.f;
    mu[c] = m;
    rstd[c] = 1.f / sqrtf(v + 1e-5f);
  }
}

// ================= phase 3c: A' = gate * relu(bn(h)); plus task losses =================
__global__ __launch_bounds__(256) void aprime_kernel(
    const float* __restrict__ h1, const float* __restrict__ h2, const float* __restrict__ h3,
    const float* __restrict__ g1, const float* __restrict__ be1,
    const float* __restrict__ g2, const float* __restrict__ be2,
    const float* __restrict__ g3, const float* __restrict__ be3,
    const float* __restrict__ mu, const float* __restrict__ rstd,
    const float* __restrict__ raw, float* __restrict__ Ap,
    const float* __restrict__ tsum, const float* __restrict__ tcnt, float* __restrict__ tl_out)
{
  if (blockIdx.x == 4096) {
    if (threadIdx.x < 4) tl_out[threadIdx.x] = tsum[threadIdx.x] / tcnt[threadIdx.x];
    return;
  }
  const int n = blockIdx.x;
  for (int c = threadIdx.x; c < 896; c += 256) {
    const float* hp; const float* gg; const float* bb; int He, hc, e;
    if (c < 128)      { hp = h1; gg = g1; bb = be1; He = 128; hc = c;       e = 1; }
    else if (c < 384) { hp = h2; gg = g2; bb = be2; He = 256; hc = c - 128; e = 2; }
    else              { hp = h3; gg = g3; bb = be3; He = 512; hc = c - 384; e = 3; }
    const float h = hp[(size_t)n * He + hc];
    float v = (h - mu[c]) * rstd[c] * gg[hc] + bb[hc];
    v = v > 0.f ? v : 0.f;
    Ap[(size_t)n * 896 + c] = raw[(size_t)n * 4 + e] * v;
  }
}

// ================= phase 4: out = A' @ OWc^T + gated biases + g0*x =================
__global__ __launch_bounds__(256) void out_gemm_kernel(
    const float* __restrict__ Ap,
    const float* __restrict__ ow1, const float* __restrict__ ow2, const float* __restrict__ ow3,
    const float* __restrict__ ob1, const float* __restrict__ ob2, const float* __restrict__ ob3,
    const float* __restrict__ X, const float* __restrict__ raw, float* __restrict__ out)
{
  __shared__ float At[32*64];
  __shared__ float Bt[32*64];
  const int n0 = blockIdx.x * 64;
  const int d0 = blockIdx.y * 64;
  const int tid = threadIdx.x;
  const int lm = tid & 63, lk4 = tid >> 6;
  const int tx = tid & 15, ty = tid >> 4;
  float acc[4][4];
#pragma unroll
  for (int i = 0; i < 4; ++i)
#pragma unroll
    for (int q = 0; q < 4; ++q) acc[i][q] = 0.f;

  for (int kb = 0; kb < 896; kb += 32) {
    const float* W; int He, ko;
    if (kb < 128)      { W = ow1; He = 128; ko = 0; }
    else if (kb < 384) { W = ow2; He = 256; ko = 128; }
    else               { W = ow3; He = 512; ko = 384; }
    const float4 a0 = *(const float4*)(Ap + (size_t)(n0+lm)*896 + kb + lk4*8);
    const float4 a1 = *(const float4*)(Ap + (size_t)(n0+lm)*896 + kb + lk4*8 + 4);
    const float4 c0 = *(const float4*)(W + (size_t)(d0+lm)*He + (kb - ko) + lk4*8);
    const float4 c1 = *(const float4*)(W + (size_t)(d0+lm)*He + (kb - ko) + lk4*8 + 4);
    __syncthreads();
    At[(lk4*8+0)*64+lm]=a0.x; At[(lk4*8+1)*64+lm]=a0.y; At[(lk4*8+2)*64+lm]=a0.z; At[(lk4*8+3)*64+lm]=a0.w;
    At[(lk4*8+4)*64+lm]=a1.x; At[(lk4*8+5)*64+lm]=a1.y; At[(lk4*8+6)*64+lm]=a1.z; At[(lk4*8+7)*64+lm]=a1.w;
    Bt[(lk4*8+0)*64+lm]=c0.x; Bt[(lk4*8+1)*64+lm]=c0.y; Bt[(lk4*8+2)*64+lm]=c0.z; Bt[(lk4*8+3)*64+lm]=c0.w;
    Bt[(lk4*8+4)*64+lm]=c1.x; Bt[(lk4*8+5)*64+lm]=c1.y; Bt[(lk4*8+6)*64+lm]=c1.z; Bt[(lk4*8+7)*64+lm]=c1.w;
    __syncthreads();
#pragma unroll
    for (int k = 0; k < 32; ++k) {
      const float4 av = *(const float4*)&At[k*64 + ty*4];
      const float4 bv = *(const float4*)&Bt[k*64 + tx*4];
      acc[0][0]=fmaf(av.x,bv.x,acc[0][0]); acc[0][1]=fmaf(av.x,bv.y,acc[0][1]); acc[0][2]=fmaf(av.x,bv.z,acc[0][2]); acc[0][3]=fmaf(av.x,bv.w,acc[0][3]);
      acc[1][0]=fmaf(av.y,bv.x,acc[1][0]); acc[1][1]=fmaf(av.y,bv.y,acc[1][1]); acc[1][2]=fmaf(av.y,bv.z,acc[1][2]); acc[1][3]=fmaf(av.y,bv.w,acc[1][3]);
      acc[2][0]=fmaf(av.z,bv.x,acc[2][0]); acc[2][1]=fmaf(av.z,bv.y,acc[2][1]); acc[2][2]=fmaf(av.z,bv.z,acc[2][2]); acc[2][3]=fmaf(av.z,bv.w,acc[2][3]);
      acc[3][0]=fmaf(av.w,bv.x,acc[3][0]); acc[3][1]=fmaf(av.w,bv.y,acc[3][1]); acc[3][2]=fmaf(av.w,bv.z,acc[3][2]); acc[3][3]=fmaf(av.w,bv.w,acc[3][3]);
    }
  }
#pragma unroll
  for (int i = 0; i < 4; ++i) {
    const int n = n0 + ty * 4 + i;
    const float4 g  = *(const float4*)(raw + (size_t)n * 4);
    const float4 xv = *(const float4*)(X + (size_t)n * 512 + d0 + tx * 4);
    const float4 o1 = *(const float4*)(ob1 + d0 + tx * 4);
    const float4 o2 = *(const float4*)(ob2 + d0 + tx * 4);
    const float4 o3 = *(const float4*)(ob3 + d0 + tx * 4);
    float4 o;
    o.x = acc[i][0] + g.x*xv.x + g.y*o1.x + g.z*o2.x + g.w*o3.x;
    o.y = acc[i][1] + g.x*xv.y + g.y*o1.y + g.z*o2.y + g.w*o3.y;
    o.z = acc[i][2] + g.x*xv.z + g.y*o1.z + g.z*o2.z + g.w*o3.z;
    o.w = acc[i][3] + g.x*xv.w + g.y*o1.w + g.z*o2.w + g.w*o3.w;
    *(float4*)(out + (size_t)n * 512 + d0 + tx * 4) = o;
  }
}

// ================= host =================
extern "C" void kernel_launch(void* const* d_in, const int* in_sizes, int n_in,
                              void* d_out, int out_size, void* d_ws, size_t ws_size,
                              hipStream_t stream) {
  const float* x    = (const float*)d_in[0];
  const int*   tids = (const int*)d_in[1];
  const float* rwih = (const float*)d_in[2];
  const float* rwhh = (const float*)d_in[3];
  const float* rbih = (const float*)d_in[4];
  const float* rbhh = (const float*)d_in[5];
  const float* row  = (const float*)d_in[6];
  const float* rob  = (const float*)d_in[7];
  const float* w1ih = (const float*)d_in[8];
  const float* w1hh = (const float*)d_in[9];
  const float* b1ih = (const float*)d_in[10];
  const float* b1hh = (const float*)d_in[11];
  const float* bn1g = (const float*)d_in[12];
  const float* bn1b = (const float*)d_in[13];
  const float* ow1  = (const float*)d_in[14];
  const float* ob1  = (const float*)d_in[15];
  const float* w2ih = (const float*)d_in[16];
  const float* w2hh = (const float*)d_in[17];
  const float* b2ih = (const float*)d_in[18];
  const float* b2hh = (const float*)d_in[19];
  const float* bn2g = (const float*)d_in[20];
  const float* bn2b = (const float*)d_in[21];
  const float* ow2  = (const float*)d_in[22];
  const float* ob2  = (const float*)d_in[23];
  const float* w3ih = (const float*)d_in[24];
  const float* w3hh = (const float*)d_in[25];
  const float* b3ih = (const float*)d_in[26];
  const float* b3hh = (const float*)d_in[27];
  const float* bn3g = (const float*)d_in[28];
  const float* bn3b = (const float*)d_in[29];
  const float* ow3  = (const float*)d_in[30];
  const float* ob3  = (const float*)d_in[31];

  char* ws = (char*)d_ws;
  float* tsum = (float*)(ws + OFF_TSUM);
  float* tcnt = (float*)(ws + OFF_TCNT);
  int*   cnt  = (int*)(ws + OFF_CNT);
  int*   done = (int*)(ws + OFF_DONE);
  float* GI   = (float*)(ws + OFF_GI);
  float* hs   = (float*)(ws + OFF_HS);
  float* ha3  = (float*)(ws + OFF_HA3);
  float* ha2  = (float*)(ws + OFF_HA2);
  float* ha1  = (float*)(ws + OFF_HA1);
  float* Ap   = (float*)(ws + OFF_AP);
  float* mu   = (float*)(ws + OFF_MU);
  float* rstd = (float*)(ws + OFF_RSTD);

  float* outp = (float*)d_out;
  float* rawp = outp + (size_t)NTOK * DD;
  float* tlp  = rawp + (size_t)NTOK * 4;

  // zero claim/done counters + task accumulators; self-poison the h-history
  // exchange buffers (value==0xAAAAAAAA is the "not ready" sentinel)
  hipMemsetAsync(ws, 0, ZBYTES, stream);
  hipMemsetAsync(ws + OFF_HS, 0xAA, POISON_BYTES, stream);

  // phase 1: input projections for router + all experts
  gemm1_kernel<<<dim3(64, 54), 256, 0, stream>>>(x, rwih, w1ih, w2ih, w3ih,
                                                 rbih, b1ih, b2ih, b3ih, GI);

  // phase 2: XCD-claimed persistent scans (52 role WGs + ~268 heater WGs)
  ScanArgs sa;
  sa.GI = GI; sa.rwhh = rwhh; sa.rbhh = rbhh; sa.hs = hs;
  sa.w1 = w1hh; sa.b1 = b1hh; sa.ha1 = ha1;
  sa.w2 = w2hh; sa.b2 = b2hh; sa.ha2 = ha2;
  sa.w3 = w3hh; sa.b3 = b3hh; sa.ha3 = ha3;
  sa.cnt = cnt; sa.done = done;
  scan_kernel<<<dim3(320), dim3(512), 0, stream>>>(sa);

  // phase 3: router head + task-loss atomics; BN stats; A' build (+ task losses)
  router_out_kernel<<<dim3(1024), 256, 0, stream>>>(hs, row, rob, tids, rawp, tsum, tcnt);
  bn_stats_kernel<<<dim3(896), 256, 0, stream>>>(ha1, ha2, ha3, mu, rstd);
  aprime_kernel<<<dim3(4097), 256, 0, stream>>>(ha1, ha2, ha3, bn1g, bn1b, bn2g, bn2b,
                                                bn3g, bn3b, mu, rstd, rawp, Ap,
                                                tsum, tcnt, tlp);

  // phase 4: gated expert-output GEMM + identity expert + gated biases
  out_gemm_kernel<<<dim3(64, 8), 256, 0, stream>>>(Ap, ow1, ow2, ow3, ob1, ob2, ob3,
                                                   x, rawp, outp);
}